// Round 7
// baseline (447.615 us; speedup 1.0000x reference)
//
#include <hip/hip_runtime.h>
#include <hip/hip_bf16.h>
#include <math.h>

#define N_ATOMS  50000
#define N_MOTIFS 50000
#define N_SEG    (N_MOTIFS + N_ATOMS)   // 100000 combined segments
#define N_INC    600000
#define N_GRAPHS 512
#define H        64
#define MOTIF_DIM 94
#define HOUT     128
#define BN_EPS   1e-5f
#define NZ       101
#define SCAN_NBLK 98                    // ceil(100000/1024)
#define TL       32                     // rows per block in the linear kernels
#define NBLK_L   ((N_ATOMS + TL - 1) / TL)   // 1563

__device__ __forceinline__ float softplus_fast(float x) {
    return fmaxf(x, 0.0f) + __logf(1.0f + __expf(-fabsf(x)));
}
__device__ __forceinline__ float gate_f(float f, float c) {
    float sig = __builtin_amdgcn_rcpf(1.0f + __expf(-f));
    return sig * softplus_fast(c);
}

// degree histogram over combined segment space: [0,50k)=motifs, [50k,100k)=atoms
__global__ __launch_bounds__(256) void count_kernel(const int* __restrict__ he,
                                                    unsigned* __restrict__ cnt) {
    int e = blockIdx.x * 256 + threadIdx.x;
    if (e >= N_INC) return;
    atomicAdd(&cnt[he[N_INC + e]], 1u);
    atomicAdd(&cnt[N_MOTIFS + he[e]], 1u);
}

// phase 1: per-block (1024 elems) sums
__global__ __launch_bounds__(256) void scan_part(const unsigned* __restrict__ cnt,
                                                 unsigned* __restrict__ part) {
    __shared__ unsigned red[256];
    int b = blockIdx.x, t = threadIdx.x;
    int i0 = b * 1024 + t * 4;
    unsigned s = 0;
#pragma unroll
    for (int i = 0; i < 4; i++) { int idx = i0 + i; if (idx < N_SEG) s += cnt[idx]; }
    red[t] = s;
    __syncthreads();
    for (int off = 128; off > 0; off >>= 1) {
        if (t < off) red[t] += red[t + off];
        __syncthreads();
    }
    if (t == 0) part[b] = red[0];
}

// phase 2: exclusive scan of 98 block sums
__global__ __launch_bounds__(128) void scan_top(const unsigned* __restrict__ part,
                                                unsigned* __restrict__ part_pre) {
    __shared__ unsigned s[128];
    int t = threadIdx.x;
    s[t] = (t < SCAN_NBLK) ? part[t] : 0u;
    __syncthreads();
    for (int off = 1; off < 128; off <<= 1) {
        unsigned add = (t >= off) ? s[t - off] : 0u;
        __syncthreads();
        s[t] += add;
        __syncthreads();
    }
    if (t < SCAN_NBLK) part_pre[t] = (t > 0) ? s[t - 1] : 0u;
}

// phase 3: block-local exclusive scan + global offset -> base, cur
__global__ __launch_bounds__(256) void scan_down(const unsigned* __restrict__ cnt,
                                                 const unsigned* __restrict__ part_pre,
                                                 unsigned* __restrict__ base,
                                                 unsigned* __restrict__ cur) {
    __shared__ unsigned s[256];
    int b = blockIdx.x, t = threadIdx.x;
    int i0 = b * 1024 + t * 4;
    unsigned c[4];
#pragma unroll
    for (int i = 0; i < 4; i++) { int idx = i0 + i; c[i] = (idx < N_SEG) ? cnt[idx] : 0u; }
    s[t] = c[0] + c[1] + c[2] + c[3];
    __syncthreads();
    for (int off = 1; off < 256; off <<= 1) {
        unsigned add = (t >= off) ? s[t - off] : 0u;
        __syncthreads();
        s[t] += add;
        __syncthreads();
    }
    unsigned pre = part_pre[b] + ((t > 0) ? s[t - 1] : 0u);
#pragma unroll
    for (int i = 0; i < 4; i++) {
        int idx = i0 + i;
        if (idx < N_SEG) { base[idx] = pre; cur[idx] = pre; pre += c[i]; }
    }
}

// XCD-partitioned CSR fill (class = blockIdx%8 -> XCD; writes only its segment groups)
__global__ __launch_bounds__(256) void fill_kernel(const int* __restrict__ he,
                                                   const int* __restrict__ atom_z,
                                                   unsigned* __restrict__ cur,
                                                   int* __restrict__ csr_val) {
    int cls = blockIdx.x & 7;
    int bi  = blockIdx.x >> 3;
    int nb  = gridDim.x >> 3;
    for (int e = bi * 256 + threadIdx.x; e < N_INC; e += nb * 256) {
        int s = he[e];
        int h = he[N_INC + e];
        if (((h >> 4) & 7) == cls) {
            unsigned p = atomicAdd(&cur[h], 1u);
            csr_val[p] = atom_z[s];
        }
        if (((s >> 4) & 7) == cls) {
            unsigned q = atomicAdd(&cur[N_MOTIFS + s], 1u);
            csr_val[q] = h;
        }
    }
}

// embed (LDS-staged table rows) + atom projection; 4 rows x 4 cols/thread,
// k-step 4 with one-iteration-ahead register prefetch of the w rows.
__global__ __launch_bounds__(256) void atom_linear(const int* __restrict__ atom_z,
                                                   const float* __restrict__ table,
                                                   const float* __restrict__ w_f,
                                                   const float* __restrict__ w_c,
                                                   float* __restrict__ a_fc) {
    __shared__ float z[TL][H];
    __shared__ int zz[TL];
    int m0 = blockIdx.x * TL;
    int tid = threadIdx.x;
    if (tid < TL) {
        int gm = m0 + tid;
        zz[tid] = (gm < N_ATOMS) ? atom_z[gm] : 0;
    }
    __syncthreads();
    for (int idx = tid; idx < TL * 16; idx += 256) {
        int m = idx >> 4, k4 = idx & 15;
        float4 v = ((const float4*)table)[(size_t)zz[m] * 16 + k4];
        *(float4*)&z[m][k4 * 4] = v;
    }
    __syncthreads();
    int rg = tid >> 5;          // 8 row groups of 4
    int cg = tid & 31;          // 32 col groups of 4 (128 outputs: f then c)
    int c0 = cg * 4;
    int sel = (c0 >= 64) ? 1 : 0;
    int jj = c0 & 63;
    const float* wsrc = (sel ? w_c : w_f) + jj;
    float acc[4][4];
#pragma unroll
    for (int i = 0; i < 4; i++)
#pragma unroll
        for (int c = 0; c < 4; c++) acc[i][c] = 0.0f;
    float4 wb0 = *(const float4*)(wsrc);
    float4 wb1 = *(const float4*)(wsrc + H);
    float4 wb2 = *(const float4*)(wsrc + 2 * H);
    float4 wb3 = *(const float4*)(wsrc + 3 * H);
    for (int k = 0; k < H - 4; k += 4) {
        float4 nw0 = *(const float4*)(wsrc + (size_t)(k + 4) * H);
        float4 nw1 = *(const float4*)(wsrc + (size_t)(k + 5) * H);
        float4 nw2 = *(const float4*)(wsrc + (size_t)(k + 6) * H);
        float4 nw3 = *(const float4*)(wsrc + (size_t)(k + 7) * H);
        float4 zv[4];
#pragma unroll
        for (int i = 0; i < 4; i++) zv[i] = *(const float4*)&z[rg * 4 + i][k];
#pragma unroll
        for (int i = 0; i < 4; i++) {
            acc[i][0] += zv[i].x * wb0.x + zv[i].y * wb1.x + zv[i].z * wb2.x + zv[i].w * wb3.x;
            acc[i][1] += zv[i].x * wb0.y + zv[i].y * wb1.y + zv[i].z * wb2.y + zv[i].w * wb3.y;
            acc[i][2] += zv[i].x * wb0.z + zv[i].y * wb1.z + zv[i].z * wb2.z + zv[i].w * wb3.z;
            acc[i][3] += zv[i].x * wb0.w + zv[i].y * wb1.w + zv[i].z * wb2.w + zv[i].w * wb3.w;
        }
        wb0 = nw0; wb1 = nw1; wb2 = nw2; wb3 = nw3;
    }
    {   // tail k = 60..63 already in wb
        float4 zv[4];
#pragma unroll
        for (int i = 0; i < 4; i++) zv[i] = *(const float4*)&z[rg * 4 + i][H - 4];
#pragma unroll
        for (int i = 0; i < 4; i++) {
            acc[i][0] += zv[i].x * wb0.x + zv[i].y * wb1.x + zv[i].z * wb2.x + zv[i].w * wb3.x;
            acc[i][1] += zv[i].x * wb0.y + zv[i].y * wb1.y + zv[i].z * wb2.y + zv[i].w * wb3.y;
            acc[i][2] += zv[i].x * wb0.z + zv[i].y * wb1.z + zv[i].z * wb2.z + zv[i].w * wb3.z;
            acc[i][3] += zv[i].x * wb0.w + zv[i].y * wb1.w + zv[i].z * wb2.w + zv[i].w * wb3.w;
        }
    }
#pragma unroll
    for (int i = 0; i < 4; i++) {
        int gm = m0 + rg * 4 + i;
        if (gm < N_ATOMS) {
#pragma unroll
            for (int c = 0; c < 4; c++)
                a_fc[(((size_t)gm * H + (jj + c)) << 1) + sel] = acc[i][c];
        }
    }
}

// hx_mean from LDS-resident embed table; CSR motif side holds atom types
#define MPB 16
__global__ __launch_bounds__(256) void hx_gather(const unsigned* __restrict__ base,
                                                 const unsigned* __restrict__ cnt,
                                                 const int* __restrict__ csr_val,
                                                 const float* __restrict__ table,
                                                 float* __restrict__ hx_mean) {
    __shared__ float tab[NZ * H];
    int tid = threadIdx.x;
    for (int idx = tid; idx < NZ * H; idx += 256) tab[idx] = table[idx];
    __syncthreads();
    int wave = tid >> 6, j = tid & 63;
    for (int w = 0; w < MPB / 4; w++) {
        int m = blockIdx.x * MPB + wave * (MPB / 4) + w;
        unsigned b = base[m];
        unsigned d = cnt[m];
        float acc = 0.0f;
        unsigned k = 0;
        for (; k + 4 <= d; k += 4) {
            int z0 = csr_val[b + k],     z1 = csr_val[b + k + 1];
            int z2 = csr_val[b + k + 2], z3 = csr_val[b + k + 3];
            acc += tab[z0 * H + j] + tab[z1 * H + j] + tab[z2 * H + j] + tab[z3 * H + j];
        }
        for (; k < d; k++) acc += tab[csr_val[b + k] * H + j];
        hx_mean[(size_t)m * H + j] = acc / fmaxf((float)d, 1.0f);
    }
}

// motif projection (K=158, rows 64:222 of w_f/w_c, +bias); 4x4 register block,
// k-step 4 with one-iteration-ahead register prefetch of the w rows.
__global__ __launch_bounds__(256) void motif_linear(const float* __restrict__ hx_mean,
                                                    const float* __restrict__ motif_attr,
                                                    const float* __restrict__ w_f,
                                                    const float* __restrict__ b_f,
                                                    const float* __restrict__ w_c,
                                                    const float* __restrict__ b_c,
                                                    float* __restrict__ m_fc) {
    __shared__ float z[TL][160];   // 158 used
    int m0 = blockIdx.x * TL;
    int tid = threadIdx.x;
    for (int idx = tid; idx < TL * 16; idx += 256) {
        int m = idx >> 4, k4 = idx & 15;
        int gm = m0 + m;
        float4 v = make_float4(0.f, 0.f, 0.f, 0.f);
        if (gm < N_MOTIFS) v = ((const float4*)hx_mean)[(size_t)gm * 16 + k4];
        *(float4*)&z[m][k4 * 4] = v;
    }
    for (int idx = tid; idx < TL * 47; idx += 256) {
        int m = idx / 47, k2 = idx % 47;
        int gm = m0 + m;
        float2 v = make_float2(0.f, 0.f);
        if (gm < N_MOTIFS) v = ((const float2*)motif_attr)[(size_t)gm * 47 + k2];
        *(float2*)&z[m][H + k2 * 2] = v;
    }
    __syncthreads();
    int rg = tid >> 5;          // 8 row groups of 4
    int cg = tid & 31;
    int c0 = cg * 4;
    int sel = (c0 >= 64) ? 1 : 0;
    int jj = c0 & 63;
    const float* wsrc = (sel ? w_c : w_f) + (size_t)H * H + jj;
    float4 bias = *(const float4*)((sel ? b_c : b_f) + jj);
    float acc[4][4];
#pragma unroll
    for (int i = 0; i < 4; i++) {
        acc[i][0] = bias.x; acc[i][1] = bias.y; acc[i][2] = bias.z; acc[i][3] = bias.w;
    }
    float4 wb0 = *(const float4*)(wsrc);
    float4 wb1 = *(const float4*)(wsrc + H);
    float4 wb2 = *(const float4*)(wsrc + 2 * H);
    float4 wb3 = *(const float4*)(wsrc + 3 * H);
    // K=158: main loop covers k=0..151 (38 iters), wb ends holding k=152..155
    for (int k = 0; k < 152; k += 4) {
        float4 nw0 = *(const float4*)(wsrc + (size_t)(k + 4) * H);
        float4 nw1 = *(const float4*)(wsrc + (size_t)(k + 5) * H);
        float4 nw2 = *(const float4*)(wsrc + (size_t)(k + 6) * H);
        float4 nw3 = *(const float4*)(wsrc + (size_t)(k + 7) * H);
        float4 zv[4];
#pragma unroll
        for (int i = 0; i < 4; i++) zv[i] = *(const float4*)&z[rg * 4 + i][k];
#pragma unroll
        for (int i = 0; i < 4; i++) {
            acc[i][0] += zv[i].x * wb0.x + zv[i].y * wb1.x + zv[i].z * wb2.x + zv[i].w * wb3.x;
            acc[i][1] += zv[i].x * wb0.y + zv[i].y * wb1.y + zv[i].z * wb2.y + zv[i].w * wb3.y;
            acc[i][2] += zv[i].x * wb0.z + zv[i].y * wb1.z + zv[i].z * wb2.z + zv[i].w * wb3.z;
            acc[i][3] += zv[i].x * wb0.w + zv[i].y * wb1.w + zv[i].z * wb2.w + zv[i].w * wb3.w;
        }
        wb0 = nw0; wb1 = nw1; wb2 = nw2; wb3 = nw3;
    }
    {   // tail k = 152..155 from wb
        float4 zv[4];
#pragma unroll
        for (int i = 0; i < 4; i++) zv[i] = *(const float4*)&z[rg * 4 + i][152];
#pragma unroll
        for (int i = 0; i < 4; i++) {
            acc[i][0] += zv[i].x * wb0.x + zv[i].y * wb1.x + zv[i].z * wb2.x + zv[i].w * wb3.x;
            acc[i][1] += zv[i].x * wb0.y + zv[i].y * wb1.y + zv[i].z * wb2.y + zv[i].w * wb3.y;
            acc[i][2] += zv[i].x * wb0.z + zv[i].y * wb1.z + zv[i].z * wb2.z + zv[i].w * wb3.z;
            acc[i][3] += zv[i].x * wb0.w + zv[i].y * wb1.w + zv[i].z * wb2.w + zv[i].w * wb3.w;
        }
    }
    {   // tail k = 156,157
        float4 w0 = *(const float4*)(wsrc + (size_t)156 * H);
        float4 w1 = *(const float4*)(wsrc + (size_t)157 * H);
        float2 zv[4];
#pragma unroll
        for (int i = 0; i < 4; i++) zv[i] = *(const float2*)&z[rg * 4 + i][156];
#pragma unroll
        for (int i = 0; i < 4; i++) {
            acc[i][0] += zv[i].x * w0.x + zv[i].y * w1.x;
            acc[i][1] += zv[i].x * w0.y + zv[i].y * w1.y;
            acc[i][2] += zv[i].x * w0.z + zv[i].y * w1.z;
            acc[i][3] += zv[i].x * w0.w + zv[i].y * w1.w;
        }
    }
#pragma unroll
    for (int i = 0; i < 4; i++) {
        int gm = m0 + rg * 4 + i;
        if (gm < N_MOTIFS) {
#pragma unroll
            for (int c = 0; c < 4; c++)
                m_fc[(((size_t)gm * H + (jj + c)) << 1) + sel] = acc[i][c];
        }
    }
}

// one wave per atom: out_mean[i] = mean_h gate(a_fc[i] + m_fc[h]); 8-deep MLP
__global__ __launch_bounds__(256) void msg_gather(const unsigned* __restrict__ base,
                                                  const unsigned* __restrict__ cnt,
                                                  const int* __restrict__ csr_val,
                                                  const float2* __restrict__ a_fc,
                                                  const float2* __restrict__ m_fc,
                                                  float* __restrict__ out_mean) {
    int i = blockIdx.x * 4 + (threadIdx.x >> 6);
    int j = threadIdx.x & 63;
    float2 a = a_fc[(size_t)i * H + j];
    unsigned b = base[N_MOTIFS + i];
    unsigned d = cnt[N_MOTIFS + i];
    float acc = 0.0f;
    unsigned k = 0;
    for (; k + 8 <= d; k += 8) {
        int hh[8];
#pragma unroll
        for (int u = 0; u < 8; u++) hh[u] = csr_val[b + k + u];
        float2 v[8];
#pragma unroll
        for (int u = 0; u < 8; u++) v[u] = m_fc[(size_t)hh[u] * H + j];
#pragma unroll
        for (int u = 0; u < 8; u++) acc += gate_f(a.x + v[u].x, a.y + v[u].y);
    }
    for (; k + 2 <= d; k += 2) {
        int h0 = csr_val[b + k], h1 = csr_val[b + k + 1];
        float2 v0 = m_fc[(size_t)h0 * H + j];
        float2 v1 = m_fc[(size_t)h1 * H + j];
        acc += gate_f(a.x + v0.x, a.y + v0.y) + gate_f(a.x + v1.x, a.y + v1.y);
    }
    for (; k < d; k++) {
        int h0 = csr_val[b + k];
        float2 v0 = m_fc[(size_t)h0 * H + j];
        acc += gate_f(a.x + v0.x, a.y + v0.y);
    }
    out_mean[(size_t)i * H + j] = acc / fmaxf((float)d, 1.0f);
}

// column-wise sum and sumsq of out_mean over atoms
__global__ __launch_bounds__(256) void bn_stats(const float* __restrict__ out_mean,
                                                float* __restrict__ bn_sum,
                                                float* __restrict__ bn_sq) {
    __shared__ float ssum[256];
    __shared__ float ssq[256];
    int j = threadIdx.x & 63;
    int row = threadIdx.x >> 6;
    float s = 0.0f, q = 0.0f;
    for (int i = blockIdx.x * 4 + row; i < N_ATOMS; i += gridDim.x * 4) {
        float v = out_mean[(size_t)i * H + j];
        s += v; q += v * v;
    }
    ssum[threadIdx.x] = s; ssq[threadIdx.x] = q;
    __syncthreads();
    if (threadIdx.x < 64) {
        float ts = ssum[j] + ssum[64 + j] + ssum[128 + j] + ssum[192 + j];
        float tq = ssq[j] + ssq[64 + j] + ssq[128 + j] + ssq[192 + j];
        atomicAdd(&bn_sum[j], ts);
        atomicAdd(&bn_sq[j], tq);
    }
}

// 513 binary searches: gstart[g] = first atom with batch >= g (batch is sorted)
__global__ __launch_bounds__(256) void graph_bounds(const int* __restrict__ batch,
                                                    int* __restrict__ gstart) {
    int g = blockIdx.x * 256 + threadIdx.x;
    if (g > N_GRAPHS) return;
    int lo = 0, hi = N_ATOMS;
    while (lo < hi) {
        int mid = (lo + hi) >> 1;
        if (batch[mid] < g) lo = mid + 1; else hi = mid;
    }
    gstart[g] = lo;
}

// one block per graph: fused BN-apply + residual(from table) + relu + mean-pool. No atomics.
__global__ __launch_bounds__(256) void pool_kernel(const float* __restrict__ out_mean,
                                                   const float* __restrict__ bn_sum,
                                                   const float* __restrict__ bn_sq,
                                                   const float* __restrict__ gamma,
                                                   const float* __restrict__ beta,
                                                   const int* __restrict__ atom_z,
                                                   const float* __restrict__ table,
                                                   const int* __restrict__ gstart,
                                                   float* __restrict__ g_mean) {
    int g = blockIdx.x;
    int s = gstart[g], e = gstart[g + 1];
    int j = threadIdx.x & 63, w = threadIdx.x >> 6;
    const float invN = 1.0f / (float)N_ATOMS;
    float mu = bn_sum[j] * invN;
    float var = bn_sq[j] * invN - mu * mu;
    float rstd = 1.0f / sqrtf(var + BN_EPS);
    float gm = gamma[j], bt = beta[j];
    float acc = 0.0f;
    for (int i = s + w; i < e; i += 4) {
        float d = out_mean[(size_t)i * H + j];
        float xv = table[(size_t)atom_z[i] * H + j];
        float o = (d - mu) * rstd * gm + bt;
        acc += fmaxf(o + xv, 0.0f);
    }
    __shared__ float red[256];
    red[threadIdx.x] = acc;
    __syncthreads();
    if (threadIdx.x < 64) {
        float t = red[j] + red[64 + j] + red[128 + j] + red[192 + j];
        g_mean[(size_t)g * H + j] = t / fmaxf((float)(e - s), 1.0f);
    }
}

// per-graph MLP head
__global__ __launch_bounds__(128) void head_kernel(const float* __restrict__ g_mean,
                                                   const float* __restrict__ w_l1,
                                                   const float* __restrict__ b_l1,
                                                   const float* __restrict__ w_out,
                                                   const float* __restrict__ b_out,
                                                   float* __restrict__ out) {
    __shared__ float gv[H];
    __shared__ float red[HOUT];
    int g = blockIdx.x, t = threadIdx.x;
    if (t < H) gv[t] = g_mean[(size_t)g * H + t];
    __syncthreads();
    float acc = b_l1[t];
    for (int k = 0; k < H; k++) acc += gv[k] * w_l1[(size_t)k * HOUT + t];
    float h = softplus_fast(acc);
    red[t] = h * w_out[t];
    __syncthreads();
    for (int s = 64; s > 0; s >>= 1) {
        if (t < s) red[t] += red[t + s];
        __syncthreads();
    }
    if (t == 0) out[g] = red[0] + b_out[0];
}

extern "C" void kernel_launch(void* const* d_in, const int* in_sizes, int n_in,
                              void* d_out, int out_size, void* d_ws, size_t ws_size,
                              hipStream_t stream) {
    const int*   atom_z     = (const int*)  d_in[0];
    const float* motif_attr = (const float*)d_in[1];
    const int*   he         = (const int*)  d_in[2];
    const int*   batch      = (const int*)  d_in[3];
    const float* table      = (const float*)d_in[4];
    const float* w_f        = (const float*)d_in[5];
    const float* b_f        = (const float*)d_in[6];
    const float* w_c        = (const float*)d_in[7];
    const float* b_c        = (const float*)d_in[8];
    const float* gamma      = (const float*)d_in[9];
    const float* beta       = (const float*)d_in[10];
    const float* w_l1       = (const float*)d_in[11];
    const float* b_l1       = (const float*)d_in[12];
    const float* w_out      = (const float*)d_in[13];
    const float* b_out      = (const float*)d_in[14];
    float* out = (float*)d_out;

    // ---- workspace layout ----
    unsigned* cnt    = (unsigned*)d_ws;                    // 100,000 (zeroed)
    float*    bn_sum = (float*)(cnt + N_SEG);              // 64
    float*    bn_sq  = bn_sum + H;                         // 64
    char*     zero_end = (char*)(bn_sq + H);
    unsigned* base     = (unsigned*)zero_end;              // 100,000
    unsigned* cur      = base + N_SEG;                     // 100,000
    unsigned* part     = cur + N_SEG;                      // 128
    unsigned* part_pre = part + 128;                       // 128
    int*      gstart   = (int*)(part_pre + 128);           // 513 (+pad)
    int*      csr_val  = gstart + 516;                     // 1,200,000
    float*    a_fc     = (float*)(csr_val + 2 * N_INC);    // 6.4M interleaved
    float*    m_fc     = a_fc + (size_t)N_ATOMS * H * 2;   // 6.4M interleaved
    float*    hx_mean  = m_fc + (size_t)N_MOTIFS * H * 2;  // 3.2M
    float*    out_mean = hx_mean;                          // alias (hx dead after motif_linear)
    float*    g_mean   = out_mean + (size_t)N_ATOMS * H;   // 32,768

    size_t zero_bytes = (size_t)(zero_end - (char*)d_ws);
    hipMemsetAsync(d_ws, 0, zero_bytes, stream);

    count_kernel<<<(N_INC + 255) / 256, 256, 0, stream>>>(he, cnt);
    scan_part<<<SCAN_NBLK, 256, 0, stream>>>(cnt, part);
    scan_top<<<1, 128, 0, stream>>>(part, part_pre);
    scan_down<<<SCAN_NBLK, 256, 0, stream>>>(cnt, part_pre, base, cur);
    fill_kernel<<<512, 256, 0, stream>>>(he, atom_z, cur, csr_val);
    graph_bounds<<<3, 256, 0, stream>>>(batch, gstart);
    atom_linear<<<NBLK_L, 256, 0, stream>>>(atom_z, table, w_f, w_c, a_fc);
    hx_gather<<<N_MOTIFS / MPB, 256, 0, stream>>>(base, cnt, csr_val, table, hx_mean);
    motif_linear<<<NBLK_L, 256, 0, stream>>>(hx_mean, motif_attr,
                                             w_f, b_f, w_c, b_c, m_fc);
    msg_gather<<<N_ATOMS / 4, 256, 0, stream>>>(base, cnt, csr_val,
                                                (const float2*)a_fc, (const float2*)m_fc,
                                                out_mean);
    bn_stats<<<1024, 256, 0, stream>>>(out_mean, bn_sum, bn_sq);
    pool_kernel<<<N_GRAPHS, 256, 0, stream>>>(out_mean, bn_sum, bn_sq, gamma, beta,
                                              atom_z, table, gstart, g_mean);
    head_kernel<<<N_GRAPHS, 128, 0, stream>>>(g_mean, w_l1, b_l1, w_out, b_out, out);
}

// Round 8
// 418.287 us; speedup vs baseline: 1.0701x; 1.0701x over previous
//
#include <hip/hip_runtime.h>
#include <hip/hip_bf16.h>
#include <math.h>

#define N_ATOMS  50000
#define N_MOTIFS 50000
#define N_SEG    (N_MOTIFS + N_ATOMS)   // 100000 combined segments
#define N_INC    600000
#define N_GRAPHS 512
#define H        64
#define MOTIF_DIM 94
#define HOUT     128
#define BN_EPS   1e-5f
#define NZ       101
#define SCAN_NBLK 98                    // ceil(100000/1024)
#define TL       64                     // rows per block in the linear kernels
                                        // NOTE: TL=32 -> compiler fully unrolls K-loop,
                                        // VGPR 56 -> 256, occupancy 8% (measured R7). Keep 64.
#define NBLK_L   ((N_ATOMS + TL - 1) / TL)   // 782

__device__ __forceinline__ float softplus_fast(float x) {
    return fmaxf(x, 0.0f) + __logf(1.0f + __expf(-fabsf(x)));
}
__device__ __forceinline__ float gate_f(float f, float c) {
    float sig = __builtin_amdgcn_rcpf(1.0f + __expf(-f));
    return sig * softplus_fast(c);
}

// degree histogram over combined segment space: [0,50k)=motifs, [50k,100k)=atoms
__global__ __launch_bounds__(256) void count_kernel(const int* __restrict__ he,
                                                    unsigned* __restrict__ cnt) {
    int e = blockIdx.x * 256 + threadIdx.x;
    if (e >= N_INC) return;
    atomicAdd(&cnt[he[N_INC + e]], 1u);
    atomicAdd(&cnt[N_MOTIFS + he[e]], 1u);
}

// phase 1: per-block (1024 elems) sums
__global__ __launch_bounds__(256) void scan_part(const unsigned* __restrict__ cnt,
                                                 unsigned* __restrict__ part) {
    __shared__ unsigned red[256];
    int b = blockIdx.x, t = threadIdx.x;
    int i0 = b * 1024 + t * 4;
    unsigned s = 0;
#pragma unroll
    for (int i = 0; i < 4; i++) { int idx = i0 + i; if (idx < N_SEG) s += cnt[idx]; }
    red[t] = s;
    __syncthreads();
    for (int off = 128; off > 0; off >>= 1) {
        if (t < off) red[t] += red[t + off];
        __syncthreads();
    }
    if (t == 0) part[b] = red[0];
}

// phase 2: exclusive scan of 98 block sums
__global__ __launch_bounds__(128) void scan_top(const unsigned* __restrict__ part,
                                                unsigned* __restrict__ part_pre) {
    __shared__ unsigned s[128];
    int t = threadIdx.x;
    s[t] = (t < SCAN_NBLK) ? part[t] : 0u;
    __syncthreads();
    for (int off = 1; off < 128; off <<= 1) {
        unsigned add = (t >= off) ? s[t - off] : 0u;
        __syncthreads();
        s[t] += add;
        __syncthreads();
    }
    if (t < SCAN_NBLK) part_pre[t] = (t > 0) ? s[t - 1] : 0u;
}

// phase 3: block-local exclusive scan + global offset -> base, cur
__global__ __launch_bounds__(256) void scan_down(const unsigned* __restrict__ cnt,
                                                 const unsigned* __restrict__ part_pre,
                                                 unsigned* __restrict__ base,
                                                 unsigned* __restrict__ cur) {
    __shared__ unsigned s[256];
    int b = blockIdx.x, t = threadIdx.x;
    int i0 = b * 1024 + t * 4;
    unsigned c[4];
#pragma unroll
    for (int i = 0; i < 4; i++) { int idx = i0 + i; c[i] = (idx < N_SEG) ? cnt[idx] : 0u; }
    s[t] = c[0] + c[1] + c[2] + c[3];
    __syncthreads();
    for (int off = 1; off < 256; off <<= 1) {
        unsigned add = (t >= off) ? s[t - off] : 0u;
        __syncthreads();
        s[t] += add;
        __syncthreads();
    }
    unsigned pre = part_pre[b] + ((t > 0) ? s[t - 1] : 0u);
#pragma unroll
    for (int i = 0; i < 4; i++) {
        int idx = i0 + i;
        if (idx < N_SEG) { base[idx] = pre; cur[idx] = pre; pre += c[i]; }
    }
}

// XCD-partitioned CSR fill (class = blockIdx%8 -> XCD; writes only its segment groups)
__global__ __launch_bounds__(256) void fill_kernel(const int* __restrict__ he,
                                                   const int* __restrict__ atom_z,
                                                   unsigned* __restrict__ cur,
                                                   int* __restrict__ csr_val) {
    int cls = blockIdx.x & 7;
    int bi  = blockIdx.x >> 3;
    int nb  = gridDim.x >> 3;
    for (int e = bi * 256 + threadIdx.x; e < N_INC; e += nb * 256) {
        int s = he[e];
        int h = he[N_INC + e];
        if (((h >> 4) & 7) == cls) {
            unsigned p = atomicAdd(&cur[h], 1u);
            csr_val[p] = atom_z[s];
        }
        if (((s >> 4) & 7) == cls) {
            unsigned q = atomicAdd(&cur[N_MOTIFS + s], 1u);
            csr_val[q] = h;
        }
    }
}

// embed (LDS-staged table rows) + atom projection; 8 rows x 4 cols/thread,
// k-step 4 with one-iteration-ahead register prefetch of the w rows.
__global__ __launch_bounds__(256) void atom_linear(const int* __restrict__ atom_z,
                                                   const float* __restrict__ table,
                                                   const float* __restrict__ w_f,
                                                   const float* __restrict__ w_c,
                                                   float* __restrict__ a_fc) {
    __shared__ float z[TL][H];
    __shared__ int zz[TL];
    int m0 = blockIdx.x * TL;
    int tid = threadIdx.x;
    if (tid < TL) {
        int gm = m0 + tid;
        zz[tid] = (gm < N_ATOMS) ? atom_z[gm] : 0;
    }
    __syncthreads();
    for (int idx = tid; idx < TL * 16; idx += 256) {
        int m = idx >> 4, k4 = idx & 15;
        float4 v = ((const float4*)table)[(size_t)zz[m] * 16 + k4];
        *(float4*)&z[m][k4 * 4] = v;
    }
    __syncthreads();
    int rg = tid >> 5;          // 8 row groups of 8
    int cg = tid & 31;          // 32 col groups of 4 (128 outputs: f then c)
    int c0 = cg * 4;
    int sel = (c0 >= 64) ? 1 : 0;
    int jj = c0 & 63;
    const float* wsrc = (sel ? w_c : w_f) + jj;
    float acc[8][4];
#pragma unroll
    for (int i = 0; i < 8; i++)
#pragma unroll
        for (int c = 0; c < 4; c++) acc[i][c] = 0.0f;
    float4 wb0 = *(const float4*)(wsrc);
    float4 wb1 = *(const float4*)(wsrc + H);
    float4 wb2 = *(const float4*)(wsrc + 2 * H);
    float4 wb3 = *(const float4*)(wsrc + 3 * H);
    for (int k = 0; k < H - 4; k += 4) {
        float4 nw0 = *(const float4*)(wsrc + (size_t)(k + 4) * H);
        float4 nw1 = *(const float4*)(wsrc + (size_t)(k + 5) * H);
        float4 nw2 = *(const float4*)(wsrc + (size_t)(k + 6) * H);
        float4 nw3 = *(const float4*)(wsrc + (size_t)(k + 7) * H);
        float4 zv[8];
#pragma unroll
        for (int i = 0; i < 8; i++) zv[i] = *(const float4*)&z[rg * 8 + i][k];
#pragma unroll
        for (int i = 0; i < 8; i++) {
            acc[i][0] += zv[i].x * wb0.x + zv[i].y * wb1.x + zv[i].z * wb2.x + zv[i].w * wb3.x;
            acc[i][1] += zv[i].x * wb0.y + zv[i].y * wb1.y + zv[i].z * wb2.y + zv[i].w * wb3.y;
            acc[i][2] += zv[i].x * wb0.z + zv[i].y * wb1.z + zv[i].z * wb2.z + zv[i].w * wb3.z;
            acc[i][3] += zv[i].x * wb0.w + zv[i].y * wb1.w + zv[i].z * wb2.w + zv[i].w * wb3.w;
        }
        wb0 = nw0; wb1 = nw1; wb2 = nw2; wb3 = nw3;
    }
    {   // tail k = 60..63 already in wb
        float4 zv[8];
#pragma unroll
        for (int i = 0; i < 8; i++) zv[i] = *(const float4*)&z[rg * 8 + i][H - 4];
#pragma unroll
        for (int i = 0; i < 8; i++) {
            acc[i][0] += zv[i].x * wb0.x + zv[i].y * wb1.x + zv[i].z * wb2.x + zv[i].w * wb3.x;
            acc[i][1] += zv[i].x * wb0.y + zv[i].y * wb1.y + zv[i].z * wb2.y + zv[i].w * wb3.y;
            acc[i][2] += zv[i].x * wb0.z + zv[i].y * wb1.z + zv[i].z * wb2.z + zv[i].w * wb3.z;
            acc[i][3] += zv[i].x * wb0.w + zv[i].y * wb1.w + zv[i].z * wb2.w + zv[i].w * wb3.w;
        }
    }
#pragma unroll
    for (int i = 0; i < 8; i++) {
        int gm = m0 + rg * 8 + i;
        if (gm < N_ATOMS) {
#pragma unroll
            for (int c = 0; c < 4; c++)
                a_fc[(((size_t)gm * H + (jj + c)) << 1) + sel] = acc[i][c];
        }
    }
}

// FUSED: hx gather (mean of embed rows, read straight from L1-hot table) into LDS z,
// then motif projection (K=158, rows 64:222 of w_f/w_c, +bias); 8x4 register block.
__global__ __launch_bounds__(256) void motif_fused(const unsigned* __restrict__ base,
                                                   const unsigned* __restrict__ cnt,
                                                   const int* __restrict__ csr_val,
                                                   const float* __restrict__ table,
                                                   const float* __restrict__ motif_attr,
                                                   const float* __restrict__ w_f,
                                                   const float* __restrict__ b_f,
                                                   const float* __restrict__ w_c,
                                                   const float* __restrict__ b_c,
                                                   float* __restrict__ m_fc) {
    __shared__ float z[TL][160];   // 158 used
    int m0 = blockIdx.x * TL;
    int tid = threadIdx.x;
    int wave = tid >> 6, j = tid & 63;
    // gather phase: each wave computes TL/4 motif means, lane = feature
    for (int w = 0; w < TL / 4; w++) {
        int m = wave * (TL / 4) + w;
        int gm = m0 + m;
        float val = 0.0f;
        if (gm < N_MOTIFS) {
            unsigned b = base[gm];
            unsigned d = cnt[gm];
            float acc = 0.0f;
            unsigned k = 0;
            for (; k + 4 <= d; k += 4) {
                int z0 = csr_val[b + k],     z1 = csr_val[b + k + 1];
                int z2 = csr_val[b + k + 2], z3 = csr_val[b + k + 3];
                acc += table[(size_t)z0 * H + j] + table[(size_t)z1 * H + j]
                     + table[(size_t)z2 * H + j] + table[(size_t)z3 * H + j];
            }
            for (; k < d; k++) acc += table[(size_t)csr_val[b + k] * H + j];
            val = acc / fmaxf((float)d, 1.0f);
        }
        z[m][j] = val;
    }
    // motif_attr staging
    for (int idx = tid; idx < TL * 47; idx += 256) {
        int m = idx / 47, k2 = idx % 47;
        int gm = m0 + m;
        float2 v = make_float2(0.f, 0.f);
        if (gm < N_MOTIFS) v = ((const float2*)motif_attr)[(size_t)gm * 47 + k2];
        *(float2*)&z[m][H + k2 * 2] = v;
    }
    __syncthreads();
    int rg = tid >> 5;
    int cg = tid & 31;
    int c0 = cg * 4;
    int sel = (c0 >= 64) ? 1 : 0;
    int jj = c0 & 63;
    const float* wsrc = (sel ? w_c : w_f) + (size_t)H * H + jj;
    float4 bias = *(const float4*)((sel ? b_c : b_f) + jj);
    float acc[8][4];
#pragma unroll
    for (int i = 0; i < 8; i++) {
        acc[i][0] = bias.x; acc[i][1] = bias.y; acc[i][2] = bias.z; acc[i][3] = bias.w;
    }
    float4 wb0 = *(const float4*)(wsrc);
    float4 wb1 = *(const float4*)(wsrc + H);
    float4 wb2 = *(const float4*)(wsrc + 2 * H);
    float4 wb3 = *(const float4*)(wsrc + 3 * H);
    // K=158: main loop covers k=0..151 (38 iters), wb ends holding k=152..155
    for (int k = 0; k < 152; k += 4) {
        float4 nw0 = *(const float4*)(wsrc + (size_t)(k + 4) * H);
        float4 nw1 = *(const float4*)(wsrc + (size_t)(k + 5) * H);
        float4 nw2 = *(const float4*)(wsrc + (size_t)(k + 6) * H);
        float4 nw3 = *(const float4*)(wsrc + (size_t)(k + 7) * H);
        float4 zv[8];
#pragma unroll
        for (int i = 0; i < 8; i++) zv[i] = *(const float4*)&z[rg * 8 + i][k];
#pragma unroll
        for (int i = 0; i < 8; i++) {
            acc[i][0] += zv[i].x * wb0.x + zv[i].y * wb1.x + zv[i].z * wb2.x + zv[i].w * wb3.x;
            acc[i][1] += zv[i].x * wb0.y + zv[i].y * wb1.y + zv[i].z * wb2.y + zv[i].w * wb3.y;
            acc[i][2] += zv[i].x * wb0.z + zv[i].y * wb1.z + zv[i].z * wb2.z + zv[i].w * wb3.z;
            acc[i][3] += zv[i].x * wb0.w + zv[i].y * wb1.w + zv[i].z * wb2.w + zv[i].w * wb3.w;
        }
        wb0 = nw0; wb1 = nw1; wb2 = nw2; wb3 = nw3;
    }
    {   // tail k = 152..155 from wb
        float4 zv[8];
#pragma unroll
        for (int i = 0; i < 8; i++) zv[i] = *(const float4*)&z[rg * 8 + i][152];
#pragma unroll
        for (int i = 0; i < 8; i++) {
            acc[i][0] += zv[i].x * wb0.x + zv[i].y * wb1.x + zv[i].z * wb2.x + zv[i].w * wb3.x;
            acc[i][1] += zv[i].x * wb0.y + zv[i].y * wb1.y + zv[i].z * wb2.y + zv[i].w * wb3.y;
            acc[i][2] += zv[i].x * wb0.z + zv[i].y * wb1.z + zv[i].z * wb2.z + zv[i].w * wb3.z;
            acc[i][3] += zv[i].x * wb0.w + zv[i].y * wb1.w + zv[i].z * wb2.w + zv[i].w * wb3.w;
        }
    }
    {   // tail k = 156,157
        float4 w0 = *(const float4*)(wsrc + (size_t)156 * H);
        float4 w1 = *(const float4*)(wsrc + (size_t)157 * H);
        float2 zv[8];
#pragma unroll
        for (int i = 0; i < 8; i++) zv[i] = *(const float2*)&z[rg * 8 + i][156];
#pragma unroll
        for (int i = 0; i < 8; i++) {
            acc[i][0] += zv[i].x * w0.x + zv[i].y * w1.x;
            acc[i][1] += zv[i].x * w0.y + zv[i].y * w1.y;
            acc[i][2] += zv[i].x * w0.z + zv[i].y * w1.z;
            acc[i][3] += zv[i].x * w0.w + zv[i].y * w1.w;
        }
    }
#pragma unroll
    for (int i = 0; i < 8; i++) {
        int gm = m0 + rg * 8 + i;
        if (gm < N_MOTIFS) {
#pragma unroll
            for (int c = 0; c < 4; c++)
                m_fc[(((size_t)gm * H + (jj + c)) << 1) + sel] = acc[i][c];
        }
    }
}

// one wave per atom: out_mean[i] = mean_h gate(a_fc[i] + m_fc[h]); 8-deep MLP
__global__ __launch_bounds__(256) void msg_gather(const unsigned* __restrict__ base,
                                                  const unsigned* __restrict__ cnt,
                                                  const int* __restrict__ csr_val,
                                                  const float2* __restrict__ a_fc,
                                                  const float2* __restrict__ m_fc,
                                                  float* __restrict__ out_mean) {
    int i = blockIdx.x * 4 + (threadIdx.x >> 6);
    int j = threadIdx.x & 63;
    float2 a = a_fc[(size_t)i * H + j];
    unsigned b = base[N_MOTIFS + i];
    unsigned d = cnt[N_MOTIFS + i];
    float acc = 0.0f;
    unsigned k = 0;
    for (; k + 8 <= d; k += 8) {
        int hh[8];
#pragma unroll
        for (int u = 0; u < 8; u++) hh[u] = csr_val[b + k + u];
        float2 v[8];
#pragma unroll
        for (int u = 0; u < 8; u++) v[u] = m_fc[(size_t)hh[u] * H + j];
#pragma unroll
        for (int u = 0; u < 8; u++) acc += gate_f(a.x + v[u].x, a.y + v[u].y);
    }
    for (; k + 2 <= d; k += 2) {
        int h0 = csr_val[b + k], h1 = csr_val[b + k + 1];
        float2 v0 = m_fc[(size_t)h0 * H + j];
        float2 v1 = m_fc[(size_t)h1 * H + j];
        acc += gate_f(a.x + v0.x, a.y + v0.y) + gate_f(a.x + v1.x, a.y + v1.y);
    }
    for (; k < d; k++) {
        int h0 = csr_val[b + k];
        float2 v0 = m_fc[(size_t)h0 * H + j];
        acc += gate_f(a.x + v0.x, a.y + v0.y);
    }
    out_mean[(size_t)i * H + j] = acc / fmaxf((float)d, 1.0f);
}

// column-wise sum and sumsq of out_mean over atoms
__global__ __launch_bounds__(256) void bn_stats(const float* __restrict__ out_mean,
                                                float* __restrict__ bn_sum,
                                                float* __restrict__ bn_sq) {
    __shared__ float ssum[256];
    __shared__ float ssq[256];
    int j = threadIdx.x & 63;
    int row = threadIdx.x >> 6;
    float s = 0.0f, q = 0.0f;
    for (int i = blockIdx.x * 4 + row; i < N_ATOMS; i += gridDim.x * 4) {
        float v = out_mean[(size_t)i * H + j];
        s += v; q += v * v;
    }
    ssum[threadIdx.x] = s; ssq[threadIdx.x] = q;
    __syncthreads();
    if (threadIdx.x < 64) {
        float ts = ssum[j] + ssum[64 + j] + ssum[128 + j] + ssum[192 + j];
        float tq = ssq[j] + ssq[64 + j] + ssq[128 + j] + ssq[192 + j];
        atomicAdd(&bn_sum[j], ts);
        atomicAdd(&bn_sq[j], tq);
    }
}

// 513 binary searches: gstart[g] = first atom with batch >= g (batch is sorted)
__global__ __launch_bounds__(256) void graph_bounds(const int* __restrict__ batch,
                                                    int* __restrict__ gstart) {
    int g = blockIdx.x * 256 + threadIdx.x;
    if (g > N_GRAPHS) return;
    int lo = 0, hi = N_ATOMS;
    while (lo < hi) {
        int mid = (lo + hi) >> 1;
        if (batch[mid] < g) lo = mid + 1; else hi = mid;
    }
    gstart[g] = lo;
}

// one block per graph: fused BN-apply + residual(from table) + relu + mean-pool. No atomics.
__global__ __launch_bounds__(256) void pool_kernel(const float* __restrict__ out_mean,
                                                   const float* __restrict__ bn_sum,
                                                   const float* __restrict__ bn_sq,
                                                   const float* __restrict__ gamma,
                                                   const float* __restrict__ beta,
                                                   const int* __restrict__ atom_z,
                                                   const float* __restrict__ table,
                                                   const int* __restrict__ gstart,
                                                   float* __restrict__ g_mean) {
    int g = blockIdx.x;
    int s = gstart[g], e = gstart[g + 1];
    int j = threadIdx.x & 63, w = threadIdx.x >> 6;
    const float invN = 1.0f / (float)N_ATOMS;
    float mu = bn_sum[j] * invN;
    float var = bn_sq[j] * invN - mu * mu;
    float rstd = 1.0f / sqrtf(var + BN_EPS);
    float gm = gamma[j], bt = beta[j];
    float acc = 0.0f;
    for (int i = s + w; i < e; i += 4) {
        float d = out_mean[(size_t)i * H + j];
        float xv = table[(size_t)atom_z[i] * H + j];
        float o = (d - mu) * rstd * gm + bt;
        acc += fmaxf(o + xv, 0.0f);
    }
    __shared__ float red[256];
    red[threadIdx.x] = acc;
    __syncthreads();
    if (threadIdx.x < 64) {
        float t = red[j] + red[64 + j] + red[128 + j] + red[192 + j];
        g_mean[(size_t)g * H + j] = t / fmaxf((float)(e - s), 1.0f);
    }
}

// per-graph MLP head
__global__ __launch_bounds__(128) void head_kernel(const float* __restrict__ g_mean,
                                                   const float* __restrict__ w_l1,
                                                   const float* __restrict__ b_l1,
                                                   const float* __restrict__ w_out,
                                                   const float* __restrict__ b_out,
                                                   float* __restrict__ out) {
    __shared__ float gv[H];
    __shared__ float red[HOUT];
    int g = blockIdx.x, t = threadIdx.x;
    if (t < H) gv[t] = g_mean[(size_t)g * H + t];
    __syncthreads();
    float acc = b_l1[t];
    for (int k = 0; k < H; k++) acc += gv[k] * w_l1[(size_t)k * HOUT + t];
    float h = softplus_fast(acc);
    red[t] = h * w_out[t];
    __syncthreads();
    for (int s = 64; s > 0; s >>= 1) {
        if (t < s) red[t] += red[t + s];
        __syncthreads();
    }
    if (t == 0) out[g] = red[0] + b_out[0];
}

extern "C" void kernel_launch(void* const* d_in, const int* in_sizes, int n_in,
                              void* d_out, int out_size, void* d_ws, size_t ws_size,
                              hipStream_t stream) {
    const int*   atom_z     = (const int*)  d_in[0];
    const float* motif_attr = (const float*)d_in[1];
    const int*   he         = (const int*)  d_in[2];
    const int*   batch      = (const int*)  d_in[3];
    const float* table      = (const float*)d_in[4];
    const float* w_f        = (const float*)d_in[5];
    const float* b_f        = (const float*)d_in[6];
    const float* w_c        = (const float*)d_in[7];
    const float* b_c        = (const float*)d_in[8];
    const float* gamma      = (const float*)d_in[9];
    const float* beta       = (const float*)d_in[10];
    const float* w_l1       = (const float*)d_in[11];
    const float* b_l1       = (const float*)d_in[12];
    const float* w_out      = (const float*)d_in[13];
    const float* b_out      = (const float*)d_in[14];
    float* out = (float*)d_out;

    // ---- workspace layout ----
    unsigned* cnt    = (unsigned*)d_ws;                    // 100,000 (zeroed)
    float*    bn_sum = (float*)(cnt + N_SEG);              // 64
    float*    bn_sq  = bn_sum + H;                         // 64
    char*     zero_end = (char*)(bn_sq + H);
    unsigned* base     = (unsigned*)zero_end;              // 100,000
    unsigned* cur      = base + N_SEG;                     // 100,000
    unsigned* part     = cur + N_SEG;                      // 128
    unsigned* part_pre = part + 128;                       // 128
    int*      gstart   = (int*)(part_pre + 128);           // 513 (+pad)
    int*      csr_val  = gstart + 516;                     // 1,200,000
    float*    a_fc     = (float*)(csr_val + 2 * N_INC);    // 6.4M interleaved
    float*    m_fc     = a_fc + (size_t)N_ATOMS * H * 2;   // 6.4M interleaved
    float*    out_mean = m_fc + (size_t)N_MOTIFS * H * 2;  // 3.2M
    float*    g_mean   = out_mean + (size_t)N_ATOMS * H;   // 32,768

    size_t zero_bytes = (size_t)(zero_end - (char*)d_ws);
    hipMemsetAsync(d_ws, 0, zero_bytes, stream);

    count_kernel<<<(N_INC + 255) / 256, 256, 0, stream>>>(he, cnt);
    scan_part<<<SCAN_NBLK, 256, 0, stream>>>(cnt, part);
    scan_top<<<1, 128, 0, stream>>>(part, part_pre);
    scan_down<<<SCAN_NBLK, 256, 0, stream>>>(cnt, part_pre, base, cur);
    fill_kernel<<<512, 256, 0, stream>>>(he, atom_z, cur, csr_val);
    graph_bounds<<<3, 256, 0, stream>>>(batch, gstart);
    atom_linear<<<NBLK_L, 256, 0, stream>>>(atom_z, table, w_f, w_c, a_fc);
    motif_fused<<<NBLK_L, 256, 0, stream>>>(base, cnt, csr_val, table, motif_attr,
                                            w_f, b_f, w_c, b_c, m_fc);
    msg_gather<<<N_ATOMS / 4, 256, 0, stream>>>(base, cnt, csr_val,
                                                (const float2*)a_fc, (const float2*)m_fc,
                                                out_mean);
    bn_stats<<<1024, 256, 0, stream>>>(out_mean, bn_sum, bn_sq);
    pool_kernel<<<N_GRAPHS, 256, 0, stream>>>(out_mean, bn_sum, bn_sq, gamma, beta,
                                              atom_z, table, gstart, g_mean);
    head_kernel<<<N_GRAPHS, 128, 0, stream>>>(g_mean, w_l1, b_l1, w_out, b_out, out);
}

// Round 9
// 375.847 us; speedup vs baseline: 1.1909x; 1.1129x over previous
//
#include <hip/hip_runtime.h>
#include <hip/hip_bf16.h>
#include <math.h>

#define N_ATOMS  50000
#define N_MOTIFS 50000
#define N_SEG    (N_MOTIFS + N_ATOMS)   // 100000 combined segments
#define N_INC    600000
#define N_GRAPHS 512
#define H        64
#define MOTIF_DIM 94
#define HOUT     128
#define BN_EPS   1e-5f
#define NZ       101
#define SCAN_NBLK 98                    // ceil(100000/1024)
#define TL       64                     // rows per block in the motif kernel
                                        // NOTE: TL=32 -> compiler fully unrolls K-loop,
                                        // VGPR 56 -> 256, occupancy 8% (measured R7). Keep 64.
#define NBLK_L   ((N_MOTIFS + TL - 1) / TL)  // 782
#define EZCAP    1664                   // LDS edge-list cap per block (mean 768, +27 sigma)

__device__ __forceinline__ float softplus_fast(float x) {
    return fmaxf(x, 0.0f) + __logf(1.0f + __expf(-fabsf(x)));
}
__device__ __forceinline__ float gate_f(float f, float c) {
    float sig = __builtin_amdgcn_rcpf(1.0f + __expf(-f));
    return sig * softplus_fast(c);
}

// degree histogram over combined segment space: [0,50k)=motifs, [50k,100k)=atoms
__global__ __launch_bounds__(256) void count_kernel(const int* __restrict__ he,
                                                    unsigned* __restrict__ cnt) {
    int e = blockIdx.x * 256 + threadIdx.x;
    if (e >= N_INC) return;
    atomicAdd(&cnt[he[N_INC + e]], 1u);
    atomicAdd(&cnt[N_MOTIFS + he[e]], 1u);
}

// phase 1: per-block (1024 elems) sums
__global__ __launch_bounds__(256) void scan_part(const unsigned* __restrict__ cnt,
                                                 unsigned* __restrict__ part) {
    __shared__ unsigned red[256];
    int b = blockIdx.x, t = threadIdx.x;
    int i0 = b * 1024 + t * 4;
    unsigned s = 0;
#pragma unroll
    for (int i = 0; i < 4; i++) { int idx = i0 + i; if (idx < N_SEG) s += cnt[idx]; }
    red[t] = s;
    __syncthreads();
    for (int off = 128; off > 0; off >>= 1) {
        if (t < off) red[t] += red[t + off];
        __syncthreads();
    }
    if (t == 0) part[b] = red[0];
}

// phase 2: exclusive scan of 98 block sums
__global__ __launch_bounds__(128) void scan_top(const unsigned* __restrict__ part,
                                                unsigned* __restrict__ part_pre) {
    __shared__ unsigned s[128];
    int t = threadIdx.x;
    s[t] = (t < SCAN_NBLK) ? part[t] : 0u;
    __syncthreads();
    for (int off = 1; off < 128; off <<= 1) {
        unsigned add = (t >= off) ? s[t - off] : 0u;
        __syncthreads();
        s[t] += add;
        __syncthreads();
    }
    if (t < SCAN_NBLK) part_pre[t] = (t > 0) ? s[t - 1] : 0u;
}

// phase 3: block-local exclusive scan + global offset -> base, cur
__global__ __launch_bounds__(256) void scan_down(const unsigned* __restrict__ cnt,
                                                 const unsigned* __restrict__ part_pre,
                                                 unsigned* __restrict__ base,
                                                 unsigned* __restrict__ cur) {
    __shared__ unsigned s[256];
    int b = blockIdx.x, t = threadIdx.x;
    int i0 = b * 1024 + t * 4;
    unsigned c[4];
#pragma unroll
    for (int i = 0; i < 4; i++) { int idx = i0 + i; c[i] = (idx < N_SEG) ? cnt[idx] : 0u; }
    s[t] = c[0] + c[1] + c[2] + c[3];
    __syncthreads();
    for (int off = 1; off < 256; off <<= 1) {
        unsigned add = (t >= off) ? s[t - off] : 0u;
        __syncthreads();
        s[t] += add;
        __syncthreads();
    }
    unsigned pre = part_pre[b] + ((t > 0) ? s[t - 1] : 0u);
#pragma unroll
    for (int i = 0; i < 4; i++) {
        int idx = i0 + i;
        if (idx < N_SEG) { base[idx] = pre; cur[idx] = pre; pre += c[i]; }
    }
}

// XCD-partitioned CSR fill (class = blockIdx%8 -> XCD; writes only its segment groups)
__global__ __launch_bounds__(256) void fill_kernel(const int* __restrict__ he,
                                                   const int* __restrict__ atom_z,
                                                   unsigned* __restrict__ cur,
                                                   int* __restrict__ csr_val) {
    int cls = blockIdx.x & 7;
    int bi  = blockIdx.x >> 3;
    int nb  = gridDim.x >> 3;
    for (int e = bi * 256 + threadIdx.x; e < N_INC; e += nb * 256) {
        int s = he[e];
        int h = he[N_INC + e];
        if (((h >> 4) & 7) == cls) {
            unsigned p = atomicAdd(&cur[h], 1u);
            csr_val[p] = atom_z[s];
        }
        if (((s >> 4) & 7) == cls) {
            unsigned q = atomicAdd(&cur[N_MOTIFS + s], 1u);
            csr_val[q] = h;
        }
    }
}

// Precompute projected embed tables (101 distinct atom types):
//   atab_fc[z][2j+sel] = table[z] @ w_{f,c}[0:64]   (atom-side projection, interleaved)
//   ptab_{f,c}[z][j]   = table[z] @ w_{f,c}[64:128] (hx-side projection)
__global__ __launch_bounds__(128) void precompute_tabs(const float* __restrict__ table,
                                                       const float* __restrict__ w_f,
                                                       const float* __restrict__ w_c,
                                                       float* __restrict__ atab_fc,
                                                       float* __restrict__ ptab_f,
                                                       float* __restrict__ ptab_c) {
    __shared__ float trow[H];
    int z = blockIdx.x, t = threadIdx.x;
    if (t < H) trow[t] = table[(size_t)z * H + t];
    __syncthreads();
    int sel = (t >= 64) ? 1 : 0;
    int jj = t & 63;
    const float* ws = sel ? w_c : w_f;
    float aacc = 0.0f, pacc = 0.0f;
    for (int k = 0; k < H; k++) {
        float tv = trow[k];
        aacc += tv * ws[(size_t)k * H + jj];
        pacc += tv * ws[(size_t)(H + k) * H + jj];
    }
    atab_fc[(size_t)z * 128 + jj * 2 + sel] = aacc;
    (sel ? ptab_c : ptab_f)[(size_t)z * H + jj] = pacc;
}

// Motif kernel: gather hx contribution IN PROJECTED SPACE (ptab rows, straight into
// output accumulators — no LDS round-trip, no gather/project barrier) + attr projection
// (K=94, w rows 128:222) with register prefetch. 8 rows x 4 cols per thread.
__global__ __launch_bounds__(256) void motif_fused(const unsigned* __restrict__ base,
                                                   const unsigned* __restrict__ cnt,
                                                   const int* __restrict__ csr_val,
                                                   const float* __restrict__ ptab_f,
                                                   const float* __restrict__ ptab_c,
                                                   const float* __restrict__ motif_attr,
                                                   const float* __restrict__ w_f,
                                                   const float* __restrict__ b_f,
                                                   const float* __restrict__ w_c,
                                                   const float* __restrict__ b_c,
                                                   float* __restrict__ m_fc) {
    __shared__ float z[TL][96];      // attr tile (94 used)
    __shared__ int   ez[EZCAP];      // block's contiguous edge list (atom types)
    __shared__ int   rowlo[TL];
    __shared__ int   rowd[TL];
    __shared__ float invd[TL];
    int m0 = blockIdx.x * TL;
    int tid = threadIdx.x;
    int mEnd = (m0 + TL < N_MOTIFS) ? (m0 + TL) : N_MOTIFS;
    unsigned blockBase = base[m0];
    int nE = (int)(base[mEnd] - blockBase);
    if (tid < TL) {
        int gm = m0 + tid;
        if (gm < N_MOTIFS) {
            unsigned d = cnt[gm];
            rowlo[tid] = (int)(base[gm] - blockBase);
            rowd[tid]  = (int)d;
            invd[tid]  = 1.0f / fmaxf((float)d, 1.0f);
        } else { rowlo[tid] = 0; rowd[tid] = 0; invd[tid] = 0.0f; }
    }
    int nStage = (nE < EZCAP) ? nE : EZCAP;
    for (int k = tid; k < nStage; k += 256) ez[k] = csr_val[blockBase + k];
    for (int idx = tid; idx < TL * 47; idx += 256) {
        int m = idx / 47, k2 = idx % 47;
        int gm = m0 + m;
        float2 v = make_float2(0.f, 0.f);
        if (gm < N_MOTIFS) v = ((const float2*)motif_attr)[(size_t)gm * 47 + k2];
        *(float2*)&z[m][k2 * 2] = v;
    }
    __syncthreads();

    int rg = tid >> 5;          // 8 row groups of 8
    int cg = tid & 31;          // 32 col groups of 4
    int c0 = cg * 4;
    int sel = (c0 >= 64) ? 1 : 0;
    int jj = c0 & 63;
    const float* ptab = sel ? ptab_c : ptab_f;

    // ---- gather phase: projected hx rows, accumulate per-(row,col4) ----
    float gacc[8][4];
#pragma unroll
    for (int i = 0; i < 8; i++)
#pragma unroll
        for (int c = 0; c < 4; c++) gacc[i][c] = 0.0f;
#pragma unroll
    for (int i = 0; i < 8; i++) {
        int r = rg * 8 + i;
        int lo = rowlo[r], d = rowd[r];
        for (int k = 0; k < d; k++) {
            int off = lo + k;
            int zz = (off < EZCAP) ? ez[off] : csr_val[blockBase + off];
            float4 p = *(const float4*)(ptab + (size_t)zz * H + jj);
            gacc[i][0] += p.x; gacc[i][1] += p.y; gacc[i][2] += p.z; gacc[i][3] += p.w;
        }
    }

    // ---- attr projection: K=94, w rows 128:222 ----
    const float* wsrc = (sel ? w_c : w_f) + (size_t)(2 * H) * H + jj;
    float4 bias = *(const float4*)((sel ? b_c : b_f) + jj);
    float acc[8][4];
#pragma unroll
    for (int i = 0; i < 8; i++) {
        acc[i][0] = bias.x; acc[i][1] = bias.y; acc[i][2] = bias.z; acc[i][3] = bias.w;
    }
    float4 wb0 = *(const float4*)(wsrc);
    float4 wb1 = *(const float4*)(wsrc + H);
    float4 wb2 = *(const float4*)(wsrc + 2 * H);
    float4 wb3 = *(const float4*)(wsrc + 3 * H);
    // main loop k=0..84 step 4 (22 iters); wb ends holding rows 88..91
    for (int k = 0; k < 88; k += 4) {
        float4 nw0 = *(const float4*)(wsrc + (size_t)(k + 4) * H);
        float4 nw1 = *(const float4*)(wsrc + (size_t)(k + 5) * H);
        float4 nw2 = *(const float4*)(wsrc + (size_t)(k + 6) * H);
        float4 nw3 = *(const float4*)(wsrc + (size_t)(k + 7) * H);
        float4 zv[8];
#pragma unroll
        for (int i = 0; i < 8; i++) zv[i] = *(const float4*)&z[rg * 8 + i][k];
#pragma unroll
        for (int i = 0; i < 8; i++) {
            acc[i][0] += zv[i].x * wb0.x + zv[i].y * wb1.x + zv[i].z * wb2.x + zv[i].w * wb3.x;
            acc[i][1] += zv[i].x * wb0.y + zv[i].y * wb1.y + zv[i].z * wb2.y + zv[i].w * wb3.y;
            acc[i][2] += zv[i].x * wb0.z + zv[i].y * wb1.z + zv[i].z * wb2.z + zv[i].w * wb3.z;
            acc[i][3] += zv[i].x * wb0.w + zv[i].y * wb1.w + zv[i].z * wb2.w + zv[i].w * wb3.w;
        }
        wb0 = nw0; wb1 = nw1; wb2 = nw2; wb3 = nw3;
    }
    {   // tail k = 88..91 from wb
        float4 zv[8];
#pragma unroll
        for (int i = 0; i < 8; i++) zv[i] = *(const float4*)&z[rg * 8 + i][88];
#pragma unroll
        for (int i = 0; i < 8; i++) {
            acc[i][0] += zv[i].x * wb0.x + zv[i].y * wb1.x + zv[i].z * wb2.x + zv[i].w * wb3.x;
            acc[i][1] += zv[i].x * wb0.y + zv[i].y * wb1.y + zv[i].z * wb2.y + zv[i].w * wb3.y;
            acc[i][2] += zv[i].x * wb0.z + zv[i].y * wb1.z + zv[i].z * wb2.z + zv[i].w * wb3.z;
            acc[i][3] += zv[i].x * wb0.w + zv[i].y * wb1.w + zv[i].z * wb2.w + zv[i].w * wb3.w;
        }
    }
    {   // tail k = 92,93
        float4 w0 = *(const float4*)(wsrc + (size_t)92 * H);
        float4 w1 = *(const float4*)(wsrc + (size_t)93 * H);
        float2 zv[8];
#pragma unroll
        for (int i = 0; i < 8; i++) zv[i] = *(const float2*)&z[rg * 8 + i][92];
#pragma unroll
        for (int i = 0; i < 8; i++) {
            acc[i][0] += zv[i].x * w0.x + zv[i].y * w1.x;
            acc[i][1] += zv[i].x * w0.y + zv[i].y * w1.y;
            acc[i][2] += zv[i].x * w0.z + zv[i].y * w1.z;
            acc[i][3] += zv[i].x * w0.w + zv[i].y * w1.w;
        }
    }
#pragma unroll
    for (int i = 0; i < 8; i++) {
        int r = rg * 8 + i;
        int gm = m0 + r;
        if (gm < N_MOTIFS) {
            float iv = invd[r];
#pragma unroll
            for (int c = 0; c < 4; c++)
                m_fc[(((size_t)gm * H + (jj + c)) << 1) + sel] = acc[i][c] + gacc[i][c] * iv;
        }
    }
}

// one wave per atom: out_mean[i] = mean_h gate(atab[z_i] + m_fc[h]); 8-deep MLP
__global__ __launch_bounds__(256) void msg_gather(const unsigned* __restrict__ base,
                                                  const unsigned* __restrict__ cnt,
                                                  const int* __restrict__ csr_val,
                                                  const int* __restrict__ atom_z,
                                                  const float2* __restrict__ atab_fc,
                                                  const float2* __restrict__ m_fc,
                                                  float* __restrict__ out_mean) {
    int i = blockIdx.x * 4 + (threadIdx.x >> 6);
    int j = threadIdx.x & 63;
    int zi = atom_z[i];                          // wave-uniform -> scalar load
    float2 a = atab_fc[(size_t)zi * H + j];
    unsigned b = base[N_MOTIFS + i];
    unsigned d = cnt[N_MOTIFS + i];
    float acc = 0.0f;
    unsigned k = 0;
    for (; k + 8 <= d; k += 8) {
        int hh[8];
#pragma unroll
        for (int u = 0; u < 8; u++) hh[u] = csr_val[b + k + u];
        float2 v[8];
#pragma unroll
        for (int u = 0; u < 8; u++) v[u] = m_fc[(size_t)hh[u] * H + j];
#pragma unroll
        for (int u = 0; u < 8; u++) acc += gate_f(a.x + v[u].x, a.y + v[u].y);
    }
    for (; k + 2 <= d; k += 2) {
        int h0 = csr_val[b + k], h1 = csr_val[b + k + 1];
        float2 v0 = m_fc[(size_t)h0 * H + j];
        float2 v1 = m_fc[(size_t)h1 * H + j];
        acc += gate_f(a.x + v0.x, a.y + v0.y) + gate_f(a.x + v1.x, a.y + v1.y);
    }
    for (; k < d; k++) {
        int h0 = csr_val[b + k];
        float2 v0 = m_fc[(size_t)h0 * H + j];
        acc += gate_f(a.x + v0.x, a.y + v0.y);
    }
    out_mean[(size_t)i * H + j] = acc / fmaxf((float)d, 1.0f);
}

// column-wise sum and sumsq of out_mean over atoms
__global__ __launch_bounds__(256) void bn_stats(const float* __restrict__ out_mean,
                                                float* __restrict__ bn_sum,
                                                float* __restrict__ bn_sq) {
    __shared__ float ssum[256];
    __shared__ float ssq[256];
    int j = threadIdx.x & 63;
    int row = threadIdx.x >> 6;
    float s = 0.0f, q = 0.0f;
    for (int i = blockIdx.x * 4 + row; i < N_ATOMS; i += gridDim.x * 4) {
        float v = out_mean[(size_t)i * H + j];
        s += v; q += v * v;
    }
    ssum[threadIdx.x] = s; ssq[threadIdx.x] = q;
    __syncthreads();
    if (threadIdx.x < 64) {
        float ts = ssum[j] + ssum[64 + j] + ssum[128 + j] + ssum[192 + j];
        float tq = ssq[j] + ssq[64 + j] + ssq[128 + j] + ssq[192 + j];
        atomicAdd(&bn_sum[j], ts);
        atomicAdd(&bn_sq[j], tq);
    }
}

// 513 binary searches: gstart[g] = first atom with batch >= g (batch is sorted)
__global__ __launch_bounds__(256) void graph_bounds(const int* __restrict__ batch,
                                                    int* __restrict__ gstart) {
    int g = blockIdx.x * 256 + threadIdx.x;
    if (g > N_GRAPHS) return;
    int lo = 0, hi = N_ATOMS;
    while (lo < hi) {
        int mid = (lo + hi) >> 1;
        if (batch[mid] < g) lo = mid + 1; else hi = mid;
    }
    gstart[g] = lo;
}

// one block per graph: fused BN-apply + residual(from table) + relu + mean-pool. No atomics.
__global__ __launch_bounds__(256) void pool_kernel(const float* __restrict__ out_mean,
                                                   const float* __restrict__ bn_sum,
                                                   const float* __restrict__ bn_sq,
                                                   const float* __restrict__ gamma,
                                                   const float* __restrict__ beta,
                                                   const int* __restrict__ atom_z,
                                                   const float* __restrict__ table,
                                                   const int* __restrict__ gstart,
                                                   float* __restrict__ g_mean) {
    int g = blockIdx.x;
    int s = gstart[g], e = gstart[g + 1];
    int j = threadIdx.x & 63, w = threadIdx.x >> 6;
    const float invN = 1.0f / (float)N_ATOMS;
    float mu = bn_sum[j] * invN;
    float var = bn_sq[j] * invN - mu * mu;
    float rstd = 1.0f / sqrtf(var + BN_EPS);
    float gm = gamma[j], bt = beta[j];
    float acc = 0.0f;
    for (int i = s + w; i < e; i += 4) {
        float d = out_mean[(size_t)i * H + j];
        float xv = table[(size_t)atom_z[i] * H + j];
        float o = (d - mu) * rstd * gm + bt;
        acc += fmaxf(o + xv, 0.0f);
    }
    __shared__ float red[256];
    red[threadIdx.x] = acc;
    __syncthreads();
    if (threadIdx.x < 64) {
        float t = red[j] + red[64 + j] + red[128 + j] + red[192 + j];
        g_mean[(size_t)g * H + j] = t / fmaxf((float)(e - s), 1.0f);
    }
}

// per-graph MLP head
__global__ __launch_bounds__(128) void head_kernel(const float* __restrict__ g_mean,
                                                   const float* __restrict__ w_l1,
                                                   const float* __restrict__ b_l1,
                                                   const float* __restrict__ w_out,
                                                   const float* __restrict__ b_out,
                                                   float* __restrict__ out) {
    __shared__ float gv[H];
    __shared__ float red[HOUT];
    int g = blockIdx.x, t = threadIdx.x;
    if (t < H) gv[t] = g_mean[(size_t)g * H + t];
    __syncthreads();
    float acc = b_l1[t];
    for (int k = 0; k < H; k++) acc += gv[k] * w_l1[(size_t)k * HOUT + t];
    float h = softplus_fast(acc);
    red[t] = h * w_out[t];
    __syncthreads();
    for (int s = 64; s > 0; s >>= 1) {
        if (t < s) red[t] += red[t + s];
        __syncthreads();
    }
    if (t == 0) out[g] = red[0] + b_out[0];
}

extern "C" void kernel_launch(void* const* d_in, const int* in_sizes, int n_in,
                              void* d_out, int out_size, void* d_ws, size_t ws_size,
                              hipStream_t stream) {
    const int*   atom_z     = (const int*)  d_in[0];
    const float* motif_attr = (const float*)d_in[1];
    const int*   he         = (const int*)  d_in[2];
    const int*   batch      = (const int*)  d_in[3];
    const float* table      = (const float*)d_in[4];
    const float* w_f        = (const float*)d_in[5];
    const float* b_f        = (const float*)d_in[6];
    const float* w_c        = (const float*)d_in[7];
    const float* b_c        = (const float*)d_in[8];
    const float* gamma      = (const float*)d_in[9];
    const float* beta       = (const float*)d_in[10];
    const float* w_l1       = (const float*)d_in[11];
    const float* b_l1       = (const float*)d_in[12];
    const float* w_out      = (const float*)d_in[13];
    const float* b_out      = (const float*)d_in[14];
    float* out = (float*)d_out;

    // ---- workspace layout ----
    unsigned* cnt    = (unsigned*)d_ws;                    // 100,000 (zeroed)
    float*    bn_sum = (float*)(cnt + N_SEG);              // 64
    float*    bn_sq  = bn_sum + H;                         // 64
    char*     zero_end = (char*)(bn_sq + H);
    unsigned* base     = (unsigned*)zero_end;              // 100,000
    unsigned* cur      = base + N_SEG;                     // 100,000
    unsigned* part     = cur + N_SEG;                      // 128
    unsigned* part_pre = part + 128;                       // 128
    int*      gstart   = (int*)(part_pre + 128);           // 513 (+pad)
    int*      csr_val  = gstart + 516;                     // 1,200,000
    float*    atab_fc  = (float*)(csr_val + 2 * N_INC);    // 101*128
    float*    ptab_f   = atab_fc + (size_t)NZ * 128;       // 101*64
    float*    ptab_c   = ptab_f + (size_t)NZ * H;          // 101*64
    float*    m_fc     = ptab_c + (size_t)NZ * H;          // 6.4M interleaved
    float*    out_mean = m_fc + (size_t)N_MOTIFS * H * 2;  // 3.2M
    float*    g_mean   = out_mean + (size_t)N_ATOMS * H;   // 32,768

    size_t zero_bytes = (size_t)(zero_end - (char*)d_ws);
    hipMemsetAsync(d_ws, 0, zero_bytes, stream);

    count_kernel<<<(N_INC + 255) / 256, 256, 0, stream>>>(he, cnt);
    scan_part<<<SCAN_NBLK, 256, 0, stream>>>(cnt, part);
    scan_top<<<1, 128, 0, stream>>>(part, part_pre);
    scan_down<<<SCAN_NBLK, 256, 0, stream>>>(cnt, part_pre, base, cur);
    fill_kernel<<<512, 256, 0, stream>>>(he, atom_z, cur, csr_val);
    graph_bounds<<<3, 256, 0, stream>>>(batch, gstart);
    precompute_tabs<<<NZ, 128, 0, stream>>>(table, w_f, w_c, atab_fc, ptab_f, ptab_c);
    motif_fused<<<NBLK_L, 256, 0, stream>>>(base, cnt, csr_val, ptab_f, ptab_c,
                                            motif_attr, w_f, b_f, w_c, b_c, m_fc);
    msg_gather<<<N_ATOMS / 4, 256, 0, stream>>>(base, cnt, csr_val, atom_z,
                                                (const float2*)atab_fc, (const float2*)m_fc,
                                                out_mean);
    bn_stats<<<1024, 256, 0, stream>>>(out_mean, bn_sum, bn_sq);
    pool_kernel<<<N_GRAPHS, 256, 0, stream>>>(out_mean, bn_sum, bn_sq, gamma, beta,
                                              atom_z, table, gstart, g_mean);
    head_kernel<<<N_GRAPHS, 128, 0, stream>>>(g_mean, w_l1, b_l1, w_out, b_out, out);
}

// Round 10
// 373.536 us; speedup vs baseline: 1.1983x; 1.0062x over previous
//
#include <hip/hip_runtime.h>
#include <hip/hip_bf16.h>
#include <math.h>

#define N_ATOMS  50000
#define N_MOTIFS 50000
#define N_SEG    (N_MOTIFS + N_ATOMS)   // 100000 combined segments
#define N_INC    600000
#define N_GRAPHS 512
#define H        64
#define MOTIF_DIM 94
#define HOUT     128
#define BN_EPS   1e-5f
#define NZ       101
#define SCAN_NBLK 98                    // ceil(100000/1024)
#define TL       64                     // motif rows per block
#define NBLK_L   ((N_MOTIFS + TL - 1) / TL)  // 782
#define EZCAP    1664                   // LDS edge-list cap per block (mean 768)

__device__ __forceinline__ float softplus_fast(float x) {
    return fmaxf(x, 0.0f) + __logf(1.0f + __expf(-fabsf(x)));
}
__device__ __forceinline__ float gate_f(float f, float c) {
    float sig = __builtin_amdgcn_rcpf(1.0f + __expf(-f));
    return sig * softplus_fast(c);
}

// degree histogram over combined segment space: [0,50k)=motifs, [50k,100k)=atoms
__global__ __launch_bounds__(256) void count_kernel(const int* __restrict__ he,
                                                    unsigned* __restrict__ cnt) {
    int e = blockIdx.x * 256 + threadIdx.x;
    if (e >= N_INC) return;
    atomicAdd(&cnt[he[N_INC + e]], 1u);
    atomicAdd(&cnt[N_MOTIFS + he[e]], 1u);
}

// phase 1: per-block (1024 elems) sums
__global__ __launch_bounds__(256) void scan_part(const unsigned* __restrict__ cnt,
                                                 unsigned* __restrict__ part) {
    __shared__ unsigned red[256];
    int b = blockIdx.x, t = threadIdx.x;
    int i0 = b * 1024 + t * 4;
    unsigned s = 0;
#pragma unroll
    for (int i = 0; i < 4; i++) { int idx = i0 + i; if (idx < N_SEG) s += cnt[idx]; }
    red[t] = s;
    __syncthreads();
    for (int off = 128; off > 0; off >>= 1) {
        if (t < off) red[t] += red[t + off];
        __syncthreads();
    }
    if (t == 0) part[b] = red[0];
}

// phase 2: exclusive scan of 98 block sums
__global__ __launch_bounds__(128) void scan_top(const unsigned* __restrict__ part,
                                                unsigned* __restrict__ part_pre) {
    __shared__ unsigned s[128];
    int t = threadIdx.x;
    s[t] = (t < SCAN_NBLK) ? part[t] : 0u;
    __syncthreads();
    for (int off = 1; off < 128; off <<= 1) {
        unsigned add = (t >= off) ? s[t - off] : 0u;
        __syncthreads();
        s[t] += add;
        __syncthreads();
    }
    if (t < SCAN_NBLK) part_pre[t] = (t > 0) ? s[t - 1] : 0u;
}

// phase 3: block-local exclusive scan + global offset -> base, cur
__global__ __launch_bounds__(256) void scan_down(const unsigned* __restrict__ cnt,
                                                 const unsigned* __restrict__ part_pre,
                                                 unsigned* __restrict__ base,
                                                 unsigned* __restrict__ cur) {
    __shared__ unsigned s[256];
    int b = blockIdx.x, t = threadIdx.x;
    int i0 = b * 1024 + t * 4;
    unsigned c[4];
#pragma unroll
    for (int i = 0; i < 4; i++) { int idx = i0 + i; c[i] = (idx < N_SEG) ? cnt[idx] : 0u; }
    s[t] = c[0] + c[1] + c[2] + c[3];
    __syncthreads();
    for (int off = 1; off < 256; off <<= 1) {
        unsigned add = (t >= off) ? s[t - off] : 0u;
        __syncthreads();
        s[t] += add;
        __syncthreads();
    }
    unsigned pre = part_pre[b] + ((t > 0) ? s[t - 1] : 0u);
#pragma unroll
    for (int i = 0; i < 4; i++) {
        int idx = i0 + i;
        if (idx < N_SEG) { base[idx] = pre; cur[idx] = pre; pre += c[i]; }
    }
}

// XCD-partitioned CSR fill (class = blockIdx%8 -> XCD; writes only its segment groups)
__global__ __launch_bounds__(256) void fill_kernel(const int* __restrict__ he,
                                                   const int* __restrict__ atom_z,
                                                   unsigned* __restrict__ cur,
                                                   int* __restrict__ csr_val) {
    int cls = blockIdx.x & 7;
    int bi  = blockIdx.x >> 3;
    int nb  = gridDim.x >> 3;
    for (int e = bi * 256 + threadIdx.x; e < N_INC; e += nb * 256) {
        int s = he[e];
        int h = he[N_INC + e];
        if (((h >> 4) & 7) == cls) {
            unsigned p = atomicAdd(&cur[h], 1u);
            csr_val[p] = atom_z[s];
        }
        if (((s >> 4) & 7) == cls) {
            unsigned q = atomicAdd(&cur[N_MOTIFS + s], 1u);
            csr_val[q] = h;
        }
    }
}

// Precompute projected embed tables (101 distinct atom types):
//   atab_fc[z][2j+sel] = table[z] @ w_{f,c}[0:64]   (atom-side projection, interleaved)
//   ptab_{f,c}[z][j]   = table[z] @ w_{f,c}[64:128] (hx-side projection)
__global__ __launch_bounds__(128) void precompute_tabs(const float* __restrict__ table,
                                                       const float* __restrict__ w_f,
                                                       const float* __restrict__ w_c,
                                                       float* __restrict__ atab_fc,
                                                       float* __restrict__ ptab_f,
                                                       float* __restrict__ ptab_c) {
    __shared__ float trow[H];
    int z = blockIdx.x, t = threadIdx.x;
    if (t < H) trow[t] = table[(size_t)z * H + t];
    __syncthreads();
    int sel = (t >= 64) ? 1 : 0;
    int jj = t & 63;
    const float* ws = sel ? w_c : w_f;
    float aacc = 0.0f, pacc = 0.0f;
    for (int k = 0; k < H; k++) {
        float tv = trow[k];
        aacc += tv * ws[(size_t)k * H + jj];
        pacc += tv * ws[(size_t)(H + k) * H + jj];
    }
    atab_fc[(size_t)z * 128 + jj * 2 + sel] = aacc;
    (sel ? ptab_c : ptab_f)[(size_t)z * H + jj] = pacc;
}

// Motif kernel, f/c split across blockIdx.y: projected-space hx gather (4-deep edge
// batching) + attr projection (K=94, unroll-pinned + register prefetch).
// 4 rows x 4 cols per thread; gather folded into acc before GEMM to free registers.
__global__ __launch_bounds__(256) void motif_fused(const unsigned* __restrict__ base,
                                                   const unsigned* __restrict__ cnt,
                                                   const int* __restrict__ csr_val,
                                                   const float* __restrict__ ptab_f,
                                                   const float* __restrict__ ptab_c,
                                                   const float* __restrict__ motif_attr,
                                                   const float* __restrict__ w_f,
                                                   const float* __restrict__ b_f,
                                                   const float* __restrict__ w_c,
                                                   const float* __restrict__ b_c,
                                                   float* __restrict__ m_fc) {
    __shared__ float z[TL][96];      // attr tile (94 used)
    __shared__ int   ez[EZCAP];      // block's contiguous edge list (atom types)
    __shared__ int   rowlo[TL];
    __shared__ int   rowd[TL];
    __shared__ float invd[TL];
    int m0 = blockIdx.x * TL;
    int sel = blockIdx.y;            // 0 = f, 1 = c
    int tid = threadIdx.x;
    int mEnd = (m0 + TL < N_MOTIFS) ? (m0 + TL) : N_MOTIFS;
    unsigned blockBase = base[m0];
    int nE = (int)(base[mEnd] - blockBase);
    if (tid < TL) {
        int gm = m0 + tid;
        if (gm < N_MOTIFS) {
            unsigned d = cnt[gm];
            rowlo[tid] = (int)(base[gm] - blockBase);
            rowd[tid]  = (int)d;
            invd[tid]  = 1.0f / fmaxf((float)d, 1.0f);
        } else { rowlo[tid] = 0; rowd[tid] = 0; invd[tid] = 0.0f; }
    }
    int nStage = (nE < EZCAP) ? nE : EZCAP;
    for (int k = tid; k < nStage; k += 256) ez[k] = csr_val[blockBase + k];
    for (int idx = tid; idx < TL * 47; idx += 256) {
        int m = idx / 47, k2 = idx % 47;
        int gm = m0 + m;
        float2 v = make_float2(0.f, 0.f);
        if (gm < N_MOTIFS) v = ((const float2*)motif_attr)[(size_t)gm * 47 + k2];
        *(float2*)&z[m][k2 * 2] = v;
    }
    __syncthreads();

    int rg = tid >> 4;          // 16 row groups of 4
    int cg = tid & 15;          // 16 col groups of 4 (64 cols this block)
    int jj = cg * 4;
    const float* ptab = sel ? ptab_c : ptab_f;

    // ---- gather phase: projected hx rows, 4 independent loads in flight ----
    float4 bias4 = *(const float4*)((sel ? b_c : b_f) + jj);
    float acc[4][4];
#pragma unroll
    for (int i = 0; i < 4; i++) {
        int r = rg * 4 + i;
        int lo = rowlo[r], d = rowd[r];
        float g0 = 0.f, g1 = 0.f, g2 = 0.f, g3 = 0.f;
        int k = 0;
        for (; k + 4 <= d; k += 4) {
            int o0 = lo + k, o1 = o0 + 1, o2 = o0 + 2, o3 = o0 + 3;
            int z0 = (o0 < EZCAP) ? ez[o0] : csr_val[blockBase + o0];
            int z1 = (o1 < EZCAP) ? ez[o1] : csr_val[blockBase + o1];
            int z2 = (o2 < EZCAP) ? ez[o2] : csr_val[blockBase + o2];
            int z3 = (o3 < EZCAP) ? ez[o3] : csr_val[blockBase + o3];
            float4 p0 = *(const float4*)(ptab + (size_t)z0 * H + jj);
            float4 p1 = *(const float4*)(ptab + (size_t)z1 * H + jj);
            float4 p2 = *(const float4*)(ptab + (size_t)z2 * H + jj);
            float4 p3 = *(const float4*)(ptab + (size_t)z3 * H + jj);
            g0 += p0.x + p1.x + p2.x + p3.x;
            g1 += p0.y + p1.y + p2.y + p3.y;
            g2 += p0.z + p1.z + p2.z + p3.z;
            g3 += p0.w + p1.w + p2.w + p3.w;
        }
        for (; k < d; k++) {
            int o0 = lo + k;
            int z0 = (o0 < EZCAP) ? ez[o0] : csr_val[blockBase + o0];
            float4 p0 = *(const float4*)(ptab + (size_t)z0 * H + jj);
            g0 += p0.x; g1 += p0.y; g2 += p0.z; g3 += p0.w;
        }
        float iv = invd[r];
        acc[i][0] = bias4.x + g0 * iv;
        acc[i][1] = bias4.y + g1 * iv;
        acc[i][2] = bias4.z + g2 * iv;
        acc[i][3] = bias4.w + g3 * iv;
    }

    // ---- attr projection: K=94, w rows 128:222, unroll pinned + prefetch ----
    const float* wsrc = (sel ? w_c : w_f) + (size_t)(2 * H) * H + jj;
    float4 wb0 = *(const float4*)(wsrc);
    float4 wb1 = *(const float4*)(wsrc + H);
    float4 wb2 = *(const float4*)(wsrc + 2 * H);
    float4 wb3 = *(const float4*)(wsrc + 3 * H);
#pragma unroll 1
    for (int k = 0; k < 88; k += 4) {
        float4 nw0 = *(const float4*)(wsrc + (size_t)(k + 4) * H);
        float4 nw1 = *(const float4*)(wsrc + (size_t)(k + 5) * H);
        float4 nw2 = *(const float4*)(wsrc + (size_t)(k + 6) * H);
        float4 nw3 = *(const float4*)(wsrc + (size_t)(k + 7) * H);
        float4 zv[4];
#pragma unroll
        for (int i = 0; i < 4; i++) zv[i] = *(const float4*)&z[rg * 4 + i][k];
#pragma unroll
        for (int i = 0; i < 4; i++) {
            acc[i][0] += zv[i].x * wb0.x + zv[i].y * wb1.x + zv[i].z * wb2.x + zv[i].w * wb3.x;
            acc[i][1] += zv[i].x * wb0.y + zv[i].y * wb1.y + zv[i].z * wb2.y + zv[i].w * wb3.y;
            acc[i][2] += zv[i].x * wb0.z + zv[i].y * wb1.z + zv[i].z * wb2.z + zv[i].w * wb3.z;
            acc[i][3] += zv[i].x * wb0.w + zv[i].y * wb1.w + zv[i].z * wb2.w + zv[i].w * wb3.w;
        }
        wb0 = nw0; wb1 = nw1; wb2 = nw2; wb3 = nw3;
    }
    {   // tail k = 88..91 from wb
        float4 zv[4];
#pragma unroll
        for (int i = 0; i < 4; i++) zv[i] = *(const float4*)&z[rg * 4 + i][88];
#pragma unroll
        for (int i = 0; i < 4; i++) {
            acc[i][0] += zv[i].x * wb0.x + zv[i].y * wb1.x + zv[i].z * wb2.x + zv[i].w * wb3.x;
            acc[i][1] += zv[i].x * wb0.y + zv[i].y * wb1.y + zv[i].z * wb2.y + zv[i].w * wb3.y;
            acc[i][2] += zv[i].x * wb0.z + zv[i].y * wb1.z + zv[i].z * wb2.z + zv[i].w * wb3.z;
            acc[i][3] += zv[i].x * wb0.w + zv[i].y * wb1.w + zv[i].z * wb2.w + zv[i].w * wb3.w;
        }
    }
    {   // tail k = 92,93
        float4 w0 = *(const float4*)(wsrc + (size_t)92 * H);
        float4 w1 = *(const float4*)(wsrc + (size_t)93 * H);
        float2 zv[4];
#pragma unroll
        for (int i = 0; i < 4; i++) zv[i] = *(const float2*)&z[rg * 4 + i][92];
#pragma unroll
        for (int i = 0; i < 4; i++) {
            acc[i][0] += zv[i].x * w0.x + zv[i].y * w1.x;
            acc[i][1] += zv[i].x * w0.y + zv[i].y * w1.y;
            acc[i][2] += zv[i].x * w0.z + zv[i].y * w1.z;
            acc[i][3] += zv[i].x * w0.w + zv[i].y * w1.w;
        }
    }
#pragma unroll
    for (int i = 0; i < 4; i++) {
        int gm = m0 + rg * 4 + i;
        if (gm < N_MOTIFS) {
#pragma unroll
            for (int c = 0; c < 4; c++)
                m_fc[(((size_t)gm * H + (jj + c)) << 1) + sel] = acc[i][c];
        }
    }
}

// one wave per atom: out_mean[i] = mean_h gate(atab[z_i] + m_fc[h]); 8-deep MLP
__global__ __launch_bounds__(256) void msg_gather(const unsigned* __restrict__ base,
                                                  const unsigned* __restrict__ cnt,
                                                  const int* __restrict__ csr_val,
                                                  const int* __restrict__ atom_z,
                                                  const float2* __restrict__ atab_fc,
                                                  const float2* __restrict__ m_fc,
                                                  float* __restrict__ out_mean) {
    int i = blockIdx.x * 4 + (threadIdx.x >> 6);
    int j = threadIdx.x & 63;
    int zi = atom_z[i];                          // wave-uniform -> scalar load
    float2 a = atab_fc[(size_t)zi * H + j];
    unsigned b = base[N_MOTIFS + i];
    unsigned d = cnt[N_MOTIFS + i];
    float acc = 0.0f;
    unsigned k = 0;
    for (; k + 8 <= d; k += 8) {
        int hh[8];
#pragma unroll
        for (int u = 0; u < 8; u++) hh[u] = csr_val[b + k + u];
        float2 v[8];
#pragma unroll
        for (int u = 0; u < 8; u++) v[u] = m_fc[(size_t)hh[u] * H + j];
#pragma unroll
        for (int u = 0; u < 8; u++) acc += gate_f(a.x + v[u].x, a.y + v[u].y);
    }
    for (; k + 2 <= d; k += 2) {
        int h0 = csr_val[b + k], h1 = csr_val[b + k + 1];
        float2 v0 = m_fc[(size_t)h0 * H + j];
        float2 v1 = m_fc[(size_t)h1 * H + j];
        acc += gate_f(a.x + v0.x, a.y + v0.y) + gate_f(a.x + v1.x, a.y + v1.y);
    }
    for (; k < d; k++) {
        int h0 = csr_val[b + k];
        float2 v0 = m_fc[(size_t)h0 * H + j];
        acc += gate_f(a.x + v0.x, a.y + v0.y);
    }
    out_mean[(size_t)i * H + j] = acc / fmaxf((float)d, 1.0f);
}

// column-wise sum and sumsq of out_mean over atoms
__global__ __launch_bounds__(256) void bn_stats(const float* __restrict__ out_mean,
                                                float* __restrict__ bn_sum,
                                                float* __restrict__ bn_sq) {
    __shared__ float ssum[256];
    __shared__ float ssq[256];
    int j = threadIdx.x & 63;
    int row = threadIdx.x >> 6;
    float s = 0.0f, q = 0.0f;
    for (int i = blockIdx.x * 4 + row; i < N_ATOMS; i += gridDim.x * 4) {
        float v = out_mean[(size_t)i * H + j];
        s += v; q += v * v;
    }
    ssum[threadIdx.x] = s; ssq[threadIdx.x] = q;
    __syncthreads();
    if (threadIdx.x < 64) {
        float ts = ssum[j] + ssum[64 + j] + ssum[128 + j] + ssum[192 + j];
        float tq = ssq[j] + ssq[64 + j] + ssq[128 + j] + ssq[192 + j];
        atomicAdd(&bn_sum[j], ts);
        atomicAdd(&bn_sq[j], tq);
    }
}

// 513 binary searches: gstart[g] = first atom with batch >= g (batch is sorted)
__global__ __launch_bounds__(256) void graph_bounds(const int* __restrict__ batch,
                                                    int* __restrict__ gstart) {
    int g = blockIdx.x * 256 + threadIdx.x;
    if (g > N_GRAPHS) return;
    int lo = 0, hi = N_ATOMS;
    while (lo < hi) {
        int mid = (lo + hi) >> 1;
        if (batch[mid] < g) lo = mid + 1; else hi = mid;
    }
    gstart[g] = lo;
}

// one block per graph: fused BN-apply + residual(from table) + relu + mean-pool. No atomics.
__global__ __launch_bounds__(256) void pool_kernel(const float* __restrict__ out_mean,
                                                   const float* __restrict__ bn_sum,
                                                   const float* __restrict__ bn_sq,
                                                   const float* __restrict__ gamma,
                                                   const float* __restrict__ beta,
                                                   const int* __restrict__ atom_z,
                                                   const float* __restrict__ table,
                                                   const int* __restrict__ gstart,
                                                   float* __restrict__ g_mean) {
    int g = blockIdx.x;
    int s = gstart[g], e = gstart[g + 1];
    int j = threadIdx.x & 63, w = threadIdx.x >> 6;
    const float invN = 1.0f / (float)N_ATOMS;
    float mu = bn_sum[j] * invN;
    float var = bn_sq[j] * invN - mu * mu;
    float rstd = 1.0f / sqrtf(var + BN_EPS);
    float gm = gamma[j], bt = beta[j];
    float acc = 0.0f;
    for (int i = s + w; i < e; i += 4) {
        float d = out_mean[(size_t)i * H + j];
        float xv = table[(size_t)atom_z[i] * H + j];
        float o = (d - mu) * rstd * gm + bt;
        acc += fmaxf(o + xv, 0.0f);
    }
    __shared__ float red[256];
    red[threadIdx.x] = acc;
    __syncthreads();
    if (threadIdx.x < 64) {
        float t = red[j] + red[64 + j] + red[128 + j] + red[192 + j];
        g_mean[(size_t)g * H + j] = t / fmaxf((float)(e - s), 1.0f);
    }
}

// per-graph MLP head
__global__ __launch_bounds__(128) void head_kernel(const float* __restrict__ g_mean,
                                                   const float* __restrict__ w_l1,
                                                   const float* __restrict__ b_l1,
                                                   const float* __restrict__ w_out,
                                                   const float* __restrict__ b_out,
                                                   float* __restrict__ out) {
    __shared__ float gv[H];
    __shared__ float red[HOUT];
    int g = blockIdx.x, t = threadIdx.x;
    if (t < H) gv[t] = g_mean[(size_t)g * H + t];
    __syncthreads();
    float acc = b_l1[t];
    for (int k = 0; k < H; k++) acc += gv[k] * w_l1[(size_t)k * HOUT + t];
    float h = softplus_fast(acc);
    red[t] = h * w_out[t];
    __syncthreads();
    for (int s = 64; s > 0; s >>= 1) {
        if (t < s) red[t] += red[t + s];
        __syncthreads();
    }
    if (t == 0) out[g] = red[0] + b_out[0];
}

extern "C" void kernel_launch(void* const* d_in, const int* in_sizes, int n_in,
                              void* d_out, int out_size, void* d_ws, size_t ws_size,
                              hipStream_t stream) {
    const int*   atom_z     = (const int*)  d_in[0];
    const float* motif_attr = (const float*)d_in[1];
    const int*   he         = (const int*)  d_in[2];
    const int*   batch      = (const int*)  d_in[3];
    const float* table      = (const float*)d_in[4];
    const float* w_f        = (const float*)d_in[5];
    const float* b_f        = (const float*)d_in[6];
    const float* w_c        = (const float*)d_in[7];
    const float* b_c        = (const float*)d_in[8];
    const float* gamma      = (const float*)d_in[9];
    const float* beta       = (const float*)d_in[10];
    const float* w_l1       = (const float*)d_in[11];
    const float* b_l1       = (const float*)d_in[12];
    const float* w_out      = (const float*)d_in[13];
    const float* b_out      = (const float*)d_in[14];
    float* out = (float*)d_out;

    // ---- workspace layout ----
    unsigned* cnt    = (unsigned*)d_ws;                    // 100,000 (zeroed)
    float*    bn_sum = (float*)(cnt + N_SEG);              // 64
    float*    bn_sq  = bn_sum + H;                         // 64
    char*     zero_end = (char*)(bn_sq + H);
    unsigned* base     = (unsigned*)zero_end;              // 100,000
    unsigned* cur      = base + N_SEG;                     // 100,000
    unsigned* part     = cur + N_SEG;                      // 128
    unsigned* part_pre = part + 128;                       // 128
    int*      gstart   = (int*)(part_pre + 128);           // 513 (+pad)
    int*      csr_val  = gstart + 516;                     // 1,200,000
    float*    atab_fc  = (float*)(csr_val + 2 * N_INC);    // 101*128
    float*    ptab_f   = atab_fc + (size_t)NZ * 128;       // 101*64
    float*    ptab_c   = ptab_f + (size_t)NZ * H;          // 101*64
    float*    m_fc     = ptab_c + (size_t)NZ * H;          // 6.4M interleaved
    float*    out_mean = m_fc + (size_t)N_MOTIFS * H * 2;  // 3.2M
    float*    g_mean   = out_mean + (size_t)N_ATOMS * H;   // 32,768

    size_t zero_bytes = (size_t)(zero_end - (char*)d_ws);
    hipMemsetAsync(d_ws, 0, zero_bytes, stream);

    count_kernel<<<(N_INC + 255) / 256, 256, 0, stream>>>(he, cnt);
    scan_part<<<SCAN_NBLK, 256, 0, stream>>>(cnt, part);
    scan_top<<<1, 128, 0, stream>>>(part, part_pre);
    scan_down<<<SCAN_NBLK, 256, 0, stream>>>(cnt, part_pre, base, cur);
    fill_kernel<<<1024, 256, 0, stream>>>(he, atom_z, cur, csr_val);
    graph_bounds<<<3, 256, 0, stream>>>(batch, gstart);
    precompute_tabs<<<NZ, 128, 0, stream>>>(table, w_f, w_c, atab_fc, ptab_f, ptab_c);
    motif_fused<<<dim3(NBLK_L, 2), 256, 0, stream>>>(base, cnt, csr_val, ptab_f, ptab_c,
                                                     motif_attr, w_f, b_f, w_c, b_c, m_fc);
    msg_gather<<<N_ATOMS / 4, 256, 0, stream>>>(base, cnt, csr_val, atom_z,
                                                (const float2*)atab_fc, (const float2*)m_fc,
                                                out_mean);
    bn_stats<<<1024, 256, 0, stream>>>(out_mean, bn_sum, bn_sq);
    pool_kernel<<<N_GRAPHS, 256, 0, stream>>>(out_mean, bn_sum, bn_sq, gamma, beta,
                                              atom_z, table, gstart, g_mean);
    head_kernel<<<N_GRAPHS, 128, 0, stream>>>(g_mean, w_l1, b_l1, w_out, b_out, out);
}

// Round 11
// 351.538 us; speedup vs baseline: 1.2733x; 1.0626x over previous
//
#include <hip/hip_runtime.h>
#include <hip/hip_bf16.h>
#include <math.h>

#define N_ATOMS  50000
#define N_MOTIFS 50000
#define N_SEG    (N_MOTIFS + N_ATOMS)   // 100000 combined segments
#define N_INC    600000
#define N_GRAPHS 512
#define H        64
#define MOTIF_DIM 94
#define HOUT     128
#define BN_EPS   1e-5f
#define NZ       101
#define SCAN_NBLK 98                    // ceil(100000/1024)
#define TL       64                     // motif rows per block
#define NBLK_L   ((N_MOTIFS + TL - 1) / TL)  // 782
#define EZCAP    1280                   // LDS edge-list cap (mean 768, +18 sigma; global fallback)

__device__ __forceinline__ float softplus_fast(float x) {
    return fmaxf(x, 0.0f) + __logf(1.0f + __expf(-fabsf(x)));
}
__device__ __forceinline__ float gate_f(float f, float c) {
    float sig = __builtin_amdgcn_rcpf(1.0f + __expf(-f));
    return sig * softplus_fast(c);
}

// degree histogram over combined segment space: [0,50k)=motifs, [50k,100k)=atoms
__global__ __launch_bounds__(256) void count_kernel(const int* __restrict__ he,
                                                    unsigned* __restrict__ cnt) {
    int e = blockIdx.x * 256 + threadIdx.x;
    if (e >= N_INC) return;
    atomicAdd(&cnt[he[N_INC + e]], 1u);
    atomicAdd(&cnt[N_MOTIFS + he[e]], 1u);
}

// phase 1: per-block (1024 elems) sums
__global__ __launch_bounds__(256) void scan_part(const unsigned* __restrict__ cnt,
                                                 unsigned* __restrict__ part) {
    __shared__ unsigned red[256];
    int b = blockIdx.x, t = threadIdx.x;
    int i0 = b * 1024 + t * 4;
    unsigned s = 0;
#pragma unroll
    for (int i = 0; i < 4; i++) { int idx = i0 + i; if (idx < N_SEG) s += cnt[idx]; }
    red[t] = s;
    __syncthreads();
    for (int off = 128; off > 0; off >>= 1) {
        if (t < off) red[t] += red[t + off];
        __syncthreads();
    }
    if (t == 0) part[b] = red[0];
}

// aux: block 0 = exclusive scan of the 98 block sums; blocks 1..NZ = projected-table
// precompute (atab_fc = table@w[0:64] interleaved; ptab_{f,c} = table@w[64:128]).
__global__ __launch_bounds__(256) void aux_kernel(const unsigned* __restrict__ part,
                                                  unsigned* __restrict__ part_pre,
                                                  const float* __restrict__ table,
                                                  const float* __restrict__ w_f,
                                                  const float* __restrict__ w_c,
                                                  float* __restrict__ atab_fc,
                                                  float* __restrict__ ptab_f,
                                                  float* __restrict__ ptab_c) {
    int t = threadIdx.x;
    if (blockIdx.x == 0) {
        __shared__ unsigned s[128];
        if (t < 128) s[t] = (t < SCAN_NBLK) ? part[t] : 0u;
        __syncthreads();
        for (int off = 1; off < 128; off <<= 1) {
            unsigned add = (t < 128 && t >= off) ? s[t - off] : 0u;
            __syncthreads();
            if (t < 128) s[t] += add;
            __syncthreads();
        }
        if (t < SCAN_NBLK) part_pre[t] = (t > 0) ? s[t - 1] : 0u;
        return;
    }
    int z = blockIdx.x - 1;
    __shared__ float trow[H];
    if (t < H) trow[t] = table[(size_t)z * H + t];
    __syncthreads();
    if (t < 128) {
        int sel = (t >= 64) ? 1 : 0;
        int jj = t & 63;
        const float* ws = sel ? w_c : w_f;
        float aacc = 0.0f, pacc = 0.0f;
        for (int k = 0; k < H; k++) {
            float tv = trow[k];
            aacc += tv * ws[(size_t)k * H + jj];
            pacc += tv * ws[(size_t)(H + k) * H + jj];
        }
        atab_fc[(size_t)z * 128 + jj * 2 + sel] = aacc;
        (sel ? ptab_c : ptab_f)[(size_t)z * H + jj] = pacc;
    }
}

// phase 3: block-local exclusive scan + global offset -> base, cur
__global__ __launch_bounds__(256) void scan_down(const unsigned* __restrict__ cnt,
                                                 const unsigned* __restrict__ part_pre,
                                                 unsigned* __restrict__ base,
                                                 unsigned* __restrict__ cur) {
    __shared__ unsigned s[256];
    int b = blockIdx.x, t = threadIdx.x;
    int i0 = b * 1024 + t * 4;
    unsigned c[4];
#pragma unroll
    for (int i = 0; i < 4; i++) { int idx = i0 + i; c[i] = (idx < N_SEG) ? cnt[idx] : 0u; }
    s[t] = c[0] + c[1] + c[2] + c[3];
    __syncthreads();
    for (int off = 1; off < 256; off <<= 1) {
        unsigned add = (t >= off) ? s[t - off] : 0u;
        __syncthreads();
        s[t] += add;
        __syncthreads();
    }
    unsigned pre = part_pre[b] + ((t > 0) ? s[t - 1] : 0u);
#pragma unroll
    for (int i = 0; i < 4; i++) {
        int idx = i0 + i;
        if (idx < N_SEG) { base[idx] = pre; cur[idx] = pre; pre += c[i]; }
    }
}

// XCD-partitioned CSR fill (class = blockIdx%8 -> XCD; writes only its segment groups)
__global__ __launch_bounds__(256) void fill_kernel(const int* __restrict__ he,
                                                   const int* __restrict__ atom_z,
                                                   unsigned* __restrict__ cur,
                                                   int* __restrict__ csr_val) {
    int cls = blockIdx.x & 7;
    int bi  = blockIdx.x >> 3;
    int nb  = gridDim.x >> 3;
    for (int e = bi * 256 + threadIdx.x; e < N_INC; e += nb * 256) {
        int s = he[e];
        int h = he[N_INC + e];
        if (((h >> 4) & 7) == cls) {
            unsigned p = atomicAdd(&cur[h], 1u);
            csr_val[p] = atom_z[s];
        }
        if (((s >> 4) & 7) == cls) {
            unsigned q = atomicAdd(&cur[N_MOTIFS + s], 1u);
            csr_val[q] = h;
        }
    }
}

// Motif kernel, f/c split across blockIdx.y; z padded to 100 (bank-safe: row stride
// 100 mod 32 = 4, the wave's 4 rows hit disjoint bank quads); outputs to separate
// contiguous planes (full-line float4 stores). 4 rows x 4 cols per thread.
__global__ __launch_bounds__(256) void motif_fused(const unsigned* __restrict__ base,
                                                   const unsigned* __restrict__ cnt,
                                                   const int* __restrict__ csr_val,
                                                   const float* __restrict__ ptab_f,
                                                   const float* __restrict__ ptab_c,
                                                   const float* __restrict__ motif_attr,
                                                   const float* __restrict__ w_f,
                                                   const float* __restrict__ b_f,
                                                   const float* __restrict__ w_c,
                                                   const float* __restrict__ b_c,
                                                   float* __restrict__ m_f,
                                                   float* __restrict__ m_c) {
    __shared__ float z[TL][100];     // attr tile (94 used; pad->stride 100 kills conflicts)
    __shared__ int   ez[EZCAP];      // block's contiguous edge list (atom types)
    __shared__ int   rowlo[TL];
    __shared__ int   rowd[TL];
    __shared__ float invd[TL];
    int m0 = blockIdx.x * TL;
    int sel = blockIdx.y;            // 0 = f, 1 = c
    int tid = threadIdx.x;
    int mEnd = (m0 + TL < N_MOTIFS) ? (m0 + TL) : N_MOTIFS;
    unsigned blockBase = base[m0];
    int nE = (int)(base[mEnd] - blockBase);
    if (tid < TL) {
        int gm = m0 + tid;
        if (gm < N_MOTIFS) {
            unsigned d = cnt[gm];
            rowlo[tid] = (int)(base[gm] - blockBase);
            rowd[tid]  = (int)d;
            invd[tid]  = 1.0f / fmaxf((float)d, 1.0f);
        } else { rowlo[tid] = 0; rowd[tid] = 0; invd[tid] = 0.0f; }
    }
    int nStage = (nE < EZCAP) ? nE : EZCAP;
    for (int k = tid; k < nStage; k += 256) ez[k] = csr_val[blockBase + k];
    for (int idx = tid; idx < TL * 47; idx += 256) {
        int m = idx / 47, k2 = idx % 47;
        int gm = m0 + m;
        float2 v = make_float2(0.f, 0.f);
        if (gm < N_MOTIFS) v = ((const float2*)motif_attr)[(size_t)gm * 47 + k2];
        *(float2*)&z[m][k2 * 2] = v;
    }
    __syncthreads();

    int rg = tid >> 4;          // 16 row groups of 4
    int cg = tid & 15;          // 16 col groups of 4 (64 cols this block)
    int jj = cg * 4;
    const float* ptab = sel ? ptab_c : ptab_f;

    // ---- gather phase: projected hx rows, 4 independent loads in flight ----
    float4 bias4 = *(const float4*)((sel ? b_c : b_f) + jj);
    float acc[4][4];
#pragma unroll
    for (int i = 0; i < 4; i++) {
        int r = rg * 4 + i;
        int lo = rowlo[r], d = rowd[r];
        float g0 = 0.f, g1 = 0.f, g2 = 0.f, g3 = 0.f;
        int k = 0;
        for (; k + 4 <= d; k += 4) {
            int o0 = lo + k, o1 = o0 + 1, o2 = o0 + 2, o3 = o0 + 3;
            int z0 = (o0 < EZCAP) ? ez[o0] : csr_val[blockBase + o0];
            int z1 = (o1 < EZCAP) ? ez[o1] : csr_val[blockBase + o1];
            int z2 = (o2 < EZCAP) ? ez[o2] : csr_val[blockBase + o2];
            int z3 = (o3 < EZCAP) ? ez[o3] : csr_val[blockBase + o3];
            float4 p0 = *(const float4*)(ptab + (size_t)z0 * H + jj);
            float4 p1 = *(const float4*)(ptab + (size_t)z1 * H + jj);
            float4 p2 = *(const float4*)(ptab + (size_t)z2 * H + jj);
            float4 p3 = *(const float4*)(ptab + (size_t)z3 * H + jj);
            g0 += p0.x + p1.x + p2.x + p3.x;
            g1 += p0.y + p1.y + p2.y + p3.y;
            g2 += p0.z + p1.z + p2.z + p3.z;
            g3 += p0.w + p1.w + p2.w + p3.w;
        }
        for (; k < d; k++) {
            int o0 = lo + k;
            int z0 = (o0 < EZCAP) ? ez[o0] : csr_val[blockBase + o0];
            float4 p0 = *(const float4*)(ptab + (size_t)z0 * H + jj);
            g0 += p0.x; g1 += p0.y; g2 += p0.z; g3 += p0.w;
        }
        float iv = invd[r];
        acc[i][0] = bias4.x + g0 * iv;
        acc[i][1] = bias4.y + g1 * iv;
        acc[i][2] = bias4.z + g2 * iv;
        acc[i][3] = bias4.w + g3 * iv;
    }

    // ---- attr projection: K=94, w rows 128:222, unroll pinned + prefetch ----
    const float* wsrc = (sel ? w_c : w_f) + (size_t)(2 * H) * H + jj;
    float4 wb0 = *(const float4*)(wsrc);
    float4 wb1 = *(const float4*)(wsrc + H);
    float4 wb2 = *(const float4*)(wsrc + 2 * H);
    float4 wb3 = *(const float4*)(wsrc + 3 * H);
#pragma unroll 1
    for (int k = 0; k < 88; k += 4) {
        float4 nw0 = *(const float4*)(wsrc + (size_t)(k + 4) * H);
        float4 nw1 = *(const float4*)(wsrc + (size_t)(k + 5) * H);
        float4 nw2 = *(const float4*)(wsrc + (size_t)(k + 6) * H);
        float4 nw3 = *(const float4*)(wsrc + (size_t)(k + 7) * H);
        float4 zv[4];
#pragma unroll
        for (int i = 0; i < 4; i++) zv[i] = *(const float4*)&z[rg * 4 + i][k];
#pragma unroll
        for (int i = 0; i < 4; i++) {
            acc[i][0] += zv[i].x * wb0.x + zv[i].y * wb1.x + zv[i].z * wb2.x + zv[i].w * wb3.x;
            acc[i][1] += zv[i].x * wb0.y + zv[i].y * wb1.y + zv[i].z * wb2.y + zv[i].w * wb3.y;
            acc[i][2] += zv[i].x * wb0.z + zv[i].y * wb1.z + zv[i].z * wb2.z + zv[i].w * wb3.z;
            acc[i][3] += zv[i].x * wb0.w + zv[i].y * wb1.w + zv[i].z * wb2.w + zv[i].w * wb3.w;
        }
        wb0 = nw0; wb1 = nw1; wb2 = nw2; wb3 = nw3;
    }
    {   // tail k = 88..91 from wb
        float4 zv[4];
#pragma unroll
        for (int i = 0; i < 4; i++) zv[i] = *(const float4*)&z[rg * 4 + i][88];
#pragma unroll
        for (int i = 0; i < 4; i++) {
            acc[i][0] += zv[i].x * wb0.x + zv[i].y * wb1.x + zv[i].z * wb2.x + zv[i].w * wb3.x;
            acc[i][1] += zv[i].x * wb0.y + zv[i].y * wb1.y + zv[i].z * wb2.y + zv[i].w * wb3.y;
            acc[i][2] += zv[i].x * wb0.z + zv[i].y * wb1.z + zv[i].z * wb2.z + zv[i].w * wb3.z;
            acc[i][3] += zv[i].x * wb0.w + zv[i].y * wb1.w + zv[i].z * wb2.w + zv[i].w * wb3.w;
        }
    }
    {   // tail k = 92,93
        float4 w0 = *(const float4*)(wsrc + (size_t)92 * H);
        float4 w1 = *(const float4*)(wsrc + (size_t)93 * H);
        float2 zv[4];
#pragma unroll
        for (int i = 0; i < 4; i++) zv[i] = *(const float2*)&z[rg * 4 + i][92];
#pragma unroll
        for (int i = 0; i < 4; i++) {
            acc[i][0] += zv[i].x * w0.x + zv[i].y * w1.x;
            acc[i][1] += zv[i].x * w0.y + zv[i].y * w1.y;
            acc[i][2] += zv[i].x * w0.z + zv[i].y * w1.z;
            acc[i][3] += zv[i].x * w0.w + zv[i].y * w1.w;
        }
    }
    float* dst = sel ? m_c : m_f;
#pragma unroll
    for (int i = 0; i < 4; i++) {
        int gm = m0 + rg * 4 + i;
        if (gm < N_MOTIFS)
            *(float4*)&dst[(size_t)gm * H + jj] =
                make_float4(acc[i][0], acc[i][1], acc[i][2], acc[i][3]);
    }
}

// one wave per atom: out_mean[i] = mean_h gate(atab[z_i] + (m_f[h], m_c[h])); 8-deep MLP
__global__ __launch_bounds__(256) void msg_gather(const unsigned* __restrict__ base,
                                                  const unsigned* __restrict__ cnt,
                                                  const int* __restrict__ csr_val,
                                                  const int* __restrict__ atom_z,
                                                  const float2* __restrict__ atab_fc,
                                                  const float* __restrict__ m_f,
                                                  const float* __restrict__ m_c,
                                                  float* __restrict__ out_mean) {
    int i = blockIdx.x * 4 + (threadIdx.x >> 6);
    int j = threadIdx.x & 63;
    int zi = atom_z[i];                          // wave-uniform -> scalar load
    float2 a = atab_fc[(size_t)zi * H + j];
    unsigned b = base[N_MOTIFS + i];
    unsigned d = cnt[N_MOTIFS + i];
    float acc = 0.0f;
    unsigned k = 0;
    for (; k + 8 <= d; k += 8) {
        int hh[8];
#pragma unroll
        for (int u = 0; u < 8; u++) hh[u] = csr_val[b + k + u];
        float vf[8], vc[8];
#pragma unroll
        for (int u = 0; u < 8; u++) vf[u] = m_f[(size_t)hh[u] * H + j];
#pragma unroll
        for (int u = 0; u < 8; u++) vc[u] = m_c[(size_t)hh[u] * H + j];
#pragma unroll
        for (int u = 0; u < 8; u++) acc += gate_f(a.x + vf[u], a.y + vc[u]);
    }
    for (; k < d; k++) {
        int h0 = csr_val[b + k];
        acc += gate_f(a.x + m_f[(size_t)h0 * H + j], a.y + m_c[(size_t)h0 * H + j]);
    }
    out_mean[(size_t)i * H + j] = acc / fmaxf((float)d, 1.0f);
}

// column-wise sum and sumsq of out_mean over atoms
__global__ __launch_bounds__(256) void bn_stats(const float* __restrict__ out_mean,
                                                float* __restrict__ bn_sum,
                                                float* __restrict__ bn_sq) {
    __shared__ float ssum[256];
    __shared__ float ssq[256];
    int j = threadIdx.x & 63;
    int row = threadIdx.x >> 6;
    float s = 0.0f, q = 0.0f;
    for (int i = blockIdx.x * 4 + row; i < N_ATOMS; i += gridDim.x * 4) {
        float v = out_mean[(size_t)i * H + j];
        s += v; q += v * v;
    }
    ssum[threadIdx.x] = s; ssq[threadIdx.x] = q;
    __syncthreads();
    if (threadIdx.x < 64) {
        float ts = ssum[j] + ssum[64 + j] + ssum[128 + j] + ssum[192 + j];
        float tq = ssq[j] + ssq[64 + j] + ssq[128 + j] + ssq[192 + j];
        atomicAdd(&bn_sum[j], ts);
        atomicAdd(&bn_sq[j], tq);
    }
}

// one block per graph: inline bounds search + BN-apply + residual + relu + mean-pool.
__global__ __launch_bounds__(256) void pool_kernel(const float* __restrict__ out_mean,
                                                   const float* __restrict__ bn_sum,
                                                   const float* __restrict__ bn_sq,
                                                   const float* __restrict__ gamma,
                                                   const float* __restrict__ beta,
                                                   const int* __restrict__ atom_z,
                                                   const float* __restrict__ table,
                                                   const int* __restrict__ batch,
                                                   float* __restrict__ g_mean) {
    int g = blockIdx.x;
    __shared__ int bounds[2];
    if (threadIdx.x < 2) {
        int target = g + threadIdx.x;
        int lo = 0, hi = N_ATOMS;
        while (lo < hi) {
            int mid = (lo + hi) >> 1;
            if (batch[mid] < target) lo = mid + 1; else hi = mid;
        }
        bounds[threadIdx.x] = lo;
    }
    __syncthreads();
    int s = bounds[0], e = bounds[1];
    int j = threadIdx.x & 63, w = threadIdx.x >> 6;
    const float invN = 1.0f / (float)N_ATOMS;
    float mu = bn_sum[j] * invN;
    float var = bn_sq[j] * invN - mu * mu;
    float rstd = 1.0f / sqrtf(var + BN_EPS);
    float gm = gamma[j], bt = beta[j];
    float acc = 0.0f;
    for (int i = s + w; i < e; i += 4) {
        float d = out_mean[(size_t)i * H + j];
        float xv = table[(size_t)atom_z[i] * H + j];
        float o = (d - mu) * rstd * gm + bt;
        acc += fmaxf(o + xv, 0.0f);
    }
    __shared__ float red[256];
    red[threadIdx.x] = acc;
    __syncthreads();
    if (threadIdx.x < 64) {
        float t = red[j] + red[64 + j] + red[128 + j] + red[192 + j];
        g_mean[(size_t)g * H + j] = t / fmaxf((float)(e - s), 1.0f);
    }
}

// per-graph MLP head
__global__ __launch_bounds__(128) void head_kernel(const float* __restrict__ g_mean,
                                                   const float* __restrict__ w_l1,
                                                   const float* __restrict__ b_l1,
                                                   const float* __restrict__ w_out,
                                                   const float* __restrict__ b_out,
                                                   float* __restrict__ out) {
    __shared__ float gv[H];
    __shared__ float red[HOUT];
    int g = blockIdx.x, t = threadIdx.x;
    if (t < H) gv[t] = g_mean[(size_t)g * H + t];
    __syncthreads();
    float acc = b_l1[t];
    for (int k = 0; k < H; k++) acc += gv[k] * w_l1[(size_t)k * HOUT + t];
    float h = softplus_fast(acc);
    red[t] = h * w_out[t];
    __syncthreads();
    for (int s = 64; s > 0; s >>= 1) {
        if (t < s) red[t] += red[t + s];
        __syncthreads();
    }
    if (t == 0) out[g] = red[0] + b_out[0];
}

extern "C" void kernel_launch(void* const* d_in, const int* in_sizes, int n_in,
                              void* d_out, int out_size, void* d_ws, size_t ws_size,
                              hipStream_t stream) {
    const int*   atom_z     = (const int*)  d_in[0];
    const float* motif_attr = (const float*)d_in[1];
    const int*   he         = (const int*)  d_in[2];
    const int*   batch      = (const int*)  d_in[3];
    const float* table      = (const float*)d_in[4];
    const float* w_f        = (const float*)d_in[5];
    const float* b_f        = (const float*)d_in[6];
    const float* w_c        = (const float*)d_in[7];
    const float* b_c        = (const float*)d_in[8];
    const float* gamma      = (const float*)d_in[9];
    const float* beta       = (const float*)d_in[10];
    const float* w_l1       = (const float*)d_in[11];
    const float* b_l1       = (const float*)d_in[12];
    const float* w_out      = (const float*)d_in[13];
    const float* b_out      = (const float*)d_in[14];
    float* out = (float*)d_out;

    // ---- workspace layout ----
    unsigned* cnt    = (unsigned*)d_ws;                    // 100,000 (zeroed)
    float*    bn_sum = (float*)(cnt + N_SEG);              // 64
    float*    bn_sq  = bn_sum + H;                         // 64
    char*     zero_end = (char*)(bn_sq + H);
    unsigned* base     = (unsigned*)zero_end;              // 100,000
    unsigned* cur      = base + N_SEG;                     // 100,000
    unsigned* part     = cur + N_SEG;                      // 128
    unsigned* part_pre = part + 128;                       // 128
    int*      csr_val  = (int*)(part_pre + 128);           // 1,200,000
    float*    atab_fc  = (float*)(csr_val + 2 * N_INC);    // 101*128
    float*    ptab_f   = atab_fc + (size_t)NZ * 128;       // 101*64
    float*    ptab_c   = ptab_f + (size_t)NZ * H;          // 101*64
    float*    m_f      = ptab_c + (size_t)NZ * H;          // 3.2M
    float*    m_c      = m_f + (size_t)N_MOTIFS * H;       // 3.2M
    float*    out_mean = m_c + (size_t)N_MOTIFS * H;       // 3.2M
    float*    g_mean   = out_mean + (size_t)N_ATOMS * H;   // 32,768

    size_t zero_bytes = (size_t)(zero_end - (char*)d_ws);
    hipMemsetAsync(d_ws, 0, zero_bytes, stream);

    count_kernel<<<(N_INC + 255) / 256, 256, 0, stream>>>(he, cnt);
    scan_part<<<SCAN_NBLK, 256, 0, stream>>>(cnt, part);
    aux_kernel<<<1 + NZ, 256, 0, stream>>>(part, part_pre, table, w_f, w_c,
                                           atab_fc, ptab_f, ptab_c);
    scan_down<<<SCAN_NBLK, 256, 0, stream>>>(cnt, part_pre, base, cur);
    fill_kernel<<<1024, 256, 0, stream>>>(he, atom_z, cur, csr_val);
    motif_fused<<<dim3(NBLK_L, 2), 256, 0, stream>>>(base, cnt, csr_val, ptab_f, ptab_c,
                                                     motif_attr, w_f, b_f, w_c, b_c,
                                                     m_f, m_c);
    msg_gather<<<N_ATOMS / 4, 256, 0, stream>>>(base, cnt, csr_val, atom_z,
                                                (const float2*)atab_fc, m_f, m_c,
                                                out_mean);
    bn_stats<<<1024, 256, 0, stream>>>(out_mean, bn_sum, bn_sq);
    pool_kernel<<<N_GRAPHS, 256, 0, stream>>>(out_mean, bn_sum, bn_sq, gamma, beta,
                                              atom_z, table, batch, g_mean);
    head_kernel<<<N_GRAPHS, 128, 0, stream>>>(g_mean, w_l1, b_l1, w_out, b_out, out);
}